// Round 10
// baseline (312.851 us; speedup 1.0000x reference)
//
#include <hip/hip_runtime.h>

// TemporalGAT on MI355X — round 10: nontemporal streaming stores on all pure
// output streams (gat_att / raw scores / t_att / t_out / out), coalesced t_out
// write from LDS tile, gat 4 blk/CU, pv 3 blk/CU. f16 2-term split MFMA.
// B=16, L=1024, F=128, H=4, D=64, HD=256, N=B*L=16384

constexpr int Bc = 16, Lc = 1024, Fc = 128, Hc = 4, Dc = 64, HDc = 256;
constexpr int Nrows = Bc * Lc;  // 16384
#define ALPHA_SLOPE 0.2f

typedef __attribute__((ext_vector_type(8))) _Float16 f16x8;
typedef __attribute__((ext_vector_type(4))) float f32x4;

enum { A_F32 = 0, A_HL = 1 };
enum { E_WHT = 2, E_STATS = 3, E_QKV = 4 };

__device__ __forceinline__ float lrelu(float x) { return x > 0.f ? x : ALPHA_SLOPE * x; }

__device__ __forceinline__ void gll16(const void* g, void* l) {
    __builtin_amdgcn_global_load_lds(
        (const __attribute__((address_space(1))) void*)g,
        (__attribute__((address_space(3))) void*)l, 16, 0, 0);
}

// f32 -> f16 conversions. A-operands: 2-term split; B-operands: single f16.
__device__ __forceinline__ unsigned short cv1(float v) {
    union { _Float16 f; unsigned short u; } c; c.f = (_Float16)v; return c.u;
}
__device__ __forceinline__ void sp2(float a, float b, unsigned& h, unsigned& l) {
    const _Float16 ha = (_Float16)a, hb = (_Float16)b;
    union { _Float16 f[2]; unsigned u; } H, L;
    H.f[0] = ha; H.f[1] = hb;
    L.f[0] = (_Float16)(a - (float)ha);
    L.f[1] = (_Float16)(b - (float)hb);
    h = H.u; l = L.u;
}
__device__ __forceinline__ void sp1(float v, unsigned short& h, unsigned short& l) {
    const _Float16 hv = (_Float16)v;
    union { _Float16 f; unsigned short u; } H, L;
    H.f = hv; L.f = (_Float16)(v - (float)hv);
    h = H.u; l = L.u;
}

// ---------------------------------------------------------------------------
// MFMA GEMM, 2-phase double-buffered, XCD-swizzled: C = A[M,K] @ Bt[N,K]^T.
// ---------------------------------------------------------------------------
template <int BM, int BN, int AMODE, int EPI>
__global__ __launch_bounds__(256, 2) void mm_k(
    const float* __restrict__ Af,
    const unsigned short* __restrict__ Agh, const unsigned short* __restrict__ Agl,
    const unsigned short* __restrict__ Bg,
    const float* __restrict__ bias,
    float* __restrict__ Cf,
    unsigned short* __restrict__ Ch, unsigned short* __restrict__ Cl,
    unsigned short* __restrict__ Ch2, unsigned short* __restrict__ Ch3,
    int K, int lda, int ldb, int ldc,
    long long zA, long long zB, long long zC, float alpha,
    const float* __restrict__ a1, const float* __restrict__ a2,
    float* __restrict__ si, float* __restrict__ sj, float* __restrict__ pstats)
{
    constexpr int ABUF = BM * 32, BBUF = BN * 32;
    __shared__ __align__(16) unsigned short SM[4 * ABUF + 2 * BBUF];
    unsigned short* const Ah_s = SM;
    unsigned short* const Al_s = SM + 2 * ABUF;
    unsigned short* const Bf_s = SM + 4 * ABUF;

    constexpr bool SWAPXY = (EPI == E_QKV);

    const int nbx = gridDim.x, nby = gridDim.y;
    int lin = blockIdx.x + nbx * (blockIdx.y + nby * blockIdx.z);
    const int ntot = nbx * nby * gridDim.z;
    lin = (lin & 7) * (ntot >> 3) + (lin >> 3);
    const int bx = lin % nbx;
    const int rem = lin / nbx;
    const int by = rem % nby;
    const int z  = rem / nby;

    if (AMODE == A_F32) { Af += (size_t)z * zA; }
    else { Agh += (size_t)z * zA; Agl += (size_t)z * zA; }
    Bg += (size_t)z * zB;
    if (Cf) Cf += (size_t)z * zC;

    constexpr int WC = (BN == 64) ? 1 : 2, WR = 4 / WC;
    constexpr int WM = BM / WR, WN = BN / WC, MF = WM / 16, NF = WN / 16;
    const int row0 = (SWAPXY ? by : bx) * BM;
    const int col0 = (SWAPXY ? bx : by) * BN;
    const int t = threadIdx.x, lane = t & 63, wid = t >> 6;
    const int fr = lane & 15, g = lane >> 4, fk = g * 8;
    const int wrow = (wid / WC) * WM, wcol = (wid % WC) * WN;
    const int rsub = lane >> 2, cbyt = (lane & 3) * 16;

    f32x4 acc[MF][NF] = {};

    auto stageB = [&](int k0, int pp) {
        #pragma unroll
        for (int q = 0; q < BN / 64; ++q) {
            const int r = wid * (BN / 4) + q * 16;
            const size_t gb = ((size_t)(col0 + r + rsub) * ldb + k0) * 2 + cbyt;
            gll16((const char*)Bg + gb, (char*)(Bf_s + pp * BBUF) + (size_t)r * 64);
        }
    };
    auto stageA = [&](int k0, int pp) {
        if (AMODE == A_HL) {
            #pragma unroll
            for (int q = 0; q < BM / 64; ++q) {
                const int r = wid * (BM / 4) + q * 16;
                const size_t gb = ((size_t)(row0 + r + rsub) * lda + k0) * 2 + cbyt;
                gll16((const char*)Agh + gb, (char*)(Ah_s + pp * ABUF) + (size_t)r * 64);
                gll16((const char*)Agl + gb, (char*)(Al_s + pp * ABUF) + (size_t)r * 64);
            }
        } else {
            const int r = t >> 1, h2 = t & 1;
            const float* srcA = Af + (size_t)(row0 + r) * lda + k0 + h2 * 16;
            const float4 v0 = ((const float4*)srcA)[0];
            const float4 v1 = ((const float4*)srcA)[1];
            const float4 v2 = ((const float4*)srcA)[2];
            const float4 v3 = ((const float4*)srcA)[3];
            unsigned hu[8], lu[8];
            sp2(v0.x, v0.y, hu[0], lu[0]); sp2(v0.z, v0.w, hu[1], lu[1]);
            sp2(v1.x, v1.y, hu[2], lu[2]); sp2(v1.z, v1.w, hu[3], lu[3]);
            sp2(v2.x, v2.y, hu[4], lu[4]); sp2(v2.z, v2.w, hu[5], lu[5]);
            sp2(v3.x, v3.y, hu[6], lu[6]); sp2(v3.z, v3.w, hu[7], lu[7]);
            uint4* dh = (uint4*)(Ah_s + pp * ABUF + r * 32 + h2 * 16);
            dh[0] = make_uint4(hu[0], hu[1], hu[2], hu[3]);
            dh[1] = make_uint4(hu[4], hu[5], hu[6], hu[7]);
            uint4* dl = (uint4*)(Al_s + pp * ABUF + r * 32 + h2 * 16);
            dl[0] = make_uint4(lu[0], lu[1], lu[2], lu[3]);
            dl[1] = make_uint4(lu[4], lu[5], lu[6], lu[7]);
        }
    };

    stageB(0, 0);
    stageA(0, 0);
    __syncthreads();

    const int NT = K / 32;
    int p = 0;
    for (int kt = 0; kt < NT; ++kt) {
        if (kt + 1 < NT) { stageB((kt + 1) * 32, p ^ 1); stageA((kt + 1) * 32, p ^ 1); }
        f16x8 ah[MF], al[MF];
        #pragma unroll
        for (int mf = 0; mf < MF; ++mf) {
            const int off = p * ABUF + (wrow + mf * 16 + fr) * 32 + fk;
            ah[mf] = *(const f16x8*)(Ah_s + off);
            al[mf] = *(const f16x8*)(Al_s + off);
        }
        #pragma unroll
        for (int nf = 0; nf < NF; ++nf) {
            const int off = p * BBUF + (wcol + nf * 16 + fr) * 32 + fk;
            const f16x8 bf = *(const f16x8*)(Bf_s + off);
            #pragma unroll
            for (int mf = 0; mf < MF; ++mf) {
                acc[mf][nf] = __builtin_amdgcn_mfma_f32_16x16x32_f16(ah[mf], bf, acc[mf][nf], 0, 0, 0);
                acc[mf][nf] = __builtin_amdgcn_mfma_f32_16x16x32_f16(al[mf], bf, acc[mf][nf], 0, 0, 0);
            }
        }
        __syncthreads();
        p ^= 1;
    }

    // ---- epilogues (C/D layout: col = lane&15, row = (lane>>4)*4 + i [m89])
    float* ts = (float*)SM;

    if (EPI == E_STATS) {
        #pragma unroll
        for (int mf = 0; mf < MF; ++mf) {
            #pragma unroll
            for (int i = 0; i < 4; ++i) {
                const size_t row = (size_t)row0 + wrow + mf * 16 + g * 4 + i;
                const size_t co = row * ldc + col0 + wcol + fr;
                #pragma unroll
                for (int nf = 0; nf < NF; ++nf) {
                    float v = acc[mf][nf][i] * alpha;
                    acc[mf][nf][i] = v;
                    __builtin_nontemporal_store(v, Cf + co + nf * 16);  // raw scores: never L2-resident by pv time
                }
            }
        }
        const int ty = by * WC + (wid % WC);
        #pragma unroll
        for (int mf = 0; mf < MF; ++mf) {
            #pragma unroll
            for (int i = 0; i < 4; ++i) {
                float m = acc[mf][0][i], s;
                #pragma unroll
                for (int nf = 1; nf < NF; ++nf) m = fmaxf(m, acc[mf][nf][i]);
                s = 0.f;
                #pragma unroll
                for (int nf = 0; nf < NF; ++nf) s += __expf(acc[mf][nf][i] - m);
                #pragma unroll
                for (int ofs = 1; ofs < 16; ofs <<= 1) {
                    const float om = __shfl_xor(m, ofs, 64);
                    const float os = __shfl_xor(s, ofs, 64);
                    const float nm = fmaxf(m, om);
                    s = s * __expf(m - nm) + os * __expf(om - nm);
                    m = nm;
                }
                if (fr == 0) {
                    const size_t row = (size_t)row0 + wrow + mf * 16 + g * 4 + i;
                    float* pp = pstats + (((size_t)z * 16 + ty) * Lc + row) * 2;
                    pp[0] = m; pp[1] = s;
                }
            }
        }
    }

    if (EPI == E_QKV) {
        float bv_[NF];
        #pragma unroll
        for (int nf = 0; nf < NF; ++nf) bv_[nf] = bias[col0 + wcol + nf * 16 + fr];
        #pragma unroll
        for (int mf = 0; mf < MF; ++mf)
            #pragma unroll
            for (int i = 0; i < 4; ++i)
                #pragma unroll
                for (int nf = 0; nf < NF; ++nf) acc[mf][nf][i] += bv_[nf];

        if (col0 < 256) {
            // Q: f16 pair write (A-operand of QK; re-read soon -> cached stores)
            #pragma unroll
            for (int mf = 0; mf < MF; ++mf) {
                #pragma unroll
                for (int i = 0; i < 4; ++i) {
                    const size_t row = (size_t)row0 + wrow + mf * 16 + g * 4 + i;
                    const size_t co = row * ldc + col0 + wcol + fr;
                    #pragma unroll
                    for (int nf = 0; nf < NF; ++nf) {
                        unsigned short hh16, ll16; sp1(acc[mf][nf][i], hh16, ll16);
                        Ch[co + nf * 16] = hh16; Cl[co + nf * 16] = ll16;
                    }
                }
            }
        } else if (col0 < 512) {
            // K: single f16 write
            const int cl0 = col0 & 255;
            #pragma unroll
            for (int mf = 0; mf < MF; ++mf) {
                #pragma unroll
                for (int i = 0; i < 4; ++i) {
                    const size_t row = (size_t)row0 + wrow + mf * 16 + g * 4 + i;
                    const size_t co = row * ldc + cl0 + wcol + fr;
                    #pragma unroll
                    for (int nf = 0; nf < NF; ++nf)
                        Ch2[co + nf * 16] = cv1(acc[mf][nf][i]);
                }
            }
        } else {
            // V: transposed single-f16 write -> VT[b][d][l]
            const int bq_ = row0 >> 10, lg0 = row0 & 1023;
            #pragma unroll
            for (int hf = 0; hf < 2; ++hf) {
                if ((wid & 1) == hf) {
                    #pragma unroll
                    for (int mf = 0; mf < MF; ++mf)
                        #pragma unroll
                        for (int i = 0; i < 4; ++i) {
                            const int rr = wrow + mf * 16 + g * 4 + i;
                            #pragma unroll
                            for (int nf = 0; nf < NF; ++nf)
                                ts[rr * 65 + nf * 16 + fr] = acc[mf][nf][i];
                        }
                }
                __syncthreads();
                const int l = t & 127, db = (t >> 7) * 32;
                #pragma unroll
                for (int dd = 0; dd < 32; ++dd) {
                    const int dl = db + dd;
                    const size_t o = ((size_t)bq_ * 256 + (col0 - 512) + hf * 64 + dl) * 1024 + lg0 + l;
                    Ch3[o] = cv1(ts[l * 65 + dl]);
                }
                __syncthreads();
            }
        }
    }

    if (EPI == E_WHT) {
        float a1v[NF], a2v[NF];
        #pragma unroll
        for (int nf = 0; nf < NF; ++nf) {
            a1v[nf] = a1[(size_t)z * Dc + nf * 16 + fr];
            a2v[nf] = a2[(size_t)z * Dc + nf * 16 + fr];
        }
        #pragma unroll
        for (int mf = 0; mf < MF; ++mf) {
            #pragma unroll
            for (int i = 0; i < 4; ++i) {
                float p1 = 0.f, p2 = 0.f;
                #pragma unroll
                for (int nf = 0; nf < NF; ++nf) {
                    p1 = fmaf(acc[mf][nf][i], a1v[nf], p1);
                    p2 = fmaf(acc[mf][nf][i], a2v[nf], p2);
                }
                #pragma unroll
                for (int ofs = 1; ofs < 16; ofs <<= 1) {
                    p1 += __shfl_xor(p1, ofs, 64);
                    p2 += __shfl_xor(p2, ofs, 64);
                }
                if (fr == 0) {
                    const int row = row0 + wrow + mf * 16 + g * 4 + i;
                    si[(size_t)z * Nrows + row] = p1;
                    sj[(size_t)z * Nrows + row] = p2;
                }
            }
        }
        #pragma unroll
        for (int mf = 0; mf < MF; ++mf)
            #pragma unroll
            for (int i = 0; i < 4; ++i) {
                const int rr = wrow + mf * 16 + g * 4 + i;
                #pragma unroll
                for (int nf = 0; nf < NF; ++nf)
                    ts[rr * 65 + nf * 16 + fr] = acc[mf][nf][i];
            }
        __syncthreads();
        const int bq_ = row0 >> 10, lg0 = row0 & 1023;
        const int l = t & 127, db = (t >> 7) * 32;
        #pragma unroll
        for (int dd = 0; dd < 32; ++dd) {
            const int d = db + dd;
            const size_t o = (((size_t)(z * 16 + bq_)) * 64 + d) * 1024 + lg0 + l;
            Ch[o] = cv1(ts[l * 65 + d]);
        }
    }
}

// ---------------------------------------------------------------------------
// Fused GAT, 2-phase, swizzled, in-block softmax stats. 4 blocks/CU.
// ---------------------------------------------------------------------------
__global__ __launch_bounds__(256, 4) void gat_k(
    const float* __restrict__ si, const float* __restrict__ sj,
    const unsigned short* __restrict__ WhTf,
    float* __restrict__ att, unsigned short* __restrict__ gouth,
    unsigned short* __restrict__ goutl)
{
    constexpr int BBUF = 64 * 32;
    __shared__ __align__(16) unsigned short SMg[2 * BBUF];
    __shared__ __align__(16) float sjs[Lc];
    __shared__ float redm[4];
    unsigned short* const Bf_s = SMg;

    int lin = blockIdx.x + 8 * blockIdx.z;
    lin = (lin & 7) * 64 + (lin >> 3);
    const int bx = lin & 7, z = lin >> 3;

    const int row0 = bx * 128;
    const int t = threadIdx.x, lane = t & 63, wid = t >> 6;
    const int fr = lane & 15, g = lane >> 4, fk = g * 8;
    const int wrow = wid * 32;
    const int hh = z >> 4, bb = z & 15;
    const int rsub = lane >> 2, cbyt = (lane & 3) * 16;

    const unsigned short* WhTf_z = WhTf + (size_t)z * 64 * 1024;
    const float* sjz = sj + (size_t)z * 1024;
    float* attz = att + ((size_t)z * 1024 + row0) * 1024;

    auto stageB = [&](int j0, int pp) {
        const int r = wid * 16;
        const size_t gb = ((size_t)(r + rsub) * 1024 + j0) * 2 + cbyt;
        gll16((const char*)WhTf_z + gb, (char*)(Bf_s + pp * BBUF) + (size_t)r * 64);
    };

    stageB(0, 0);
    ((float4*)sjs)[t] = ((const float4*)sjz)[t];
    __syncthreads();

    {
        const float4 v = ((const float4*)sjs)[t];
        float m4 = fmaxf(fmaxf(v.x, v.y), fmaxf(v.z, v.w));
        #pragma unroll
        for (int ofs = 32; ofs >= 1; ofs >>= 1) m4 = fmaxf(m4, __shfl_xor(m4, ofs, 64));
        if (lane == 0) redm[wid] = m4;
    }
    __syncthreads();
    const float smax = fmaxf(fmaxf(redm[0], redm[1]), fmaxf(redm[2], redm[3]));

    float siv[2], mr[2], inv[2];
    #pragma unroll
    for (int mf = 0; mf < 2; ++mf) {
        const int r = row0 + wrow + mf * 16 + fr;
        const float sv = si[(size_t)hh * Nrows + bb * 1024 + r];
        siv[mf] = sv;
        mr[mf] = lrelu(sv + smax);
        float s = 0.f;
        const float4* sp = (const float4*)sjs + g * 64;
        #pragma unroll 4
        for (int c = 0; c < 64; ++c) {
            const float4 w = sp[c];
            s += __expf(lrelu(sv + w.x) - mr[mf]) + __expf(lrelu(sv + w.y) - mr[mf])
               + __expf(lrelu(sv + w.z) - mr[mf]) + __expf(lrelu(sv + w.w) - mr[mf]);
        }
        s += __shfl_xor(s, 16, 64);
        s += __shfl_xor(s, 32, 64);
        inv[mf] = 1.0f / s;
    }

    f32x4 acc[2][4] = {};
    int p = 0;
    for (int kt = 0; kt < 32; ++kt) {
        const int j0 = kt * 32;
        if (kt < 31) stageB(j0 + 32, p ^ 1);
        f16x8 ph[2], pl[2];
        #pragma unroll
        for (int mf = 0; mf < 2; ++mf) {
            const float4 s0 = ((const float4*)sjs)[(j0 >> 2) + g * 2];
            const float4 s1 = ((const float4*)sjs)[(j0 >> 2) + g * 2 + 1];
            float pr[8];
            pr[0] = __expf(lrelu(siv[mf] + s0.x) - mr[mf]) * inv[mf];
            pr[1] = __expf(lrelu(siv[mf] + s0.y) - mr[mf]) * inv[mf];
            pr[2] = __expf(lrelu(siv[mf] + s0.z) - mr[mf]) * inv[mf];
            pr[3] = __expf(lrelu(siv[mf] + s0.w) - mr[mf]) * inv[mf];
            pr[4] = __expf(lrelu(siv[mf] + s1.x) - mr[mf]) * inv[mf];
            pr[5] = __expf(lrelu(siv[mf] + s1.y) - mr[mf]) * inv[mf];
            pr[6] = __expf(lrelu(siv[mf] + s1.z) - mr[mf]) * inv[mf];
            pr[7] = __expf(lrelu(siv[mf] + s1.w) - mr[mf]) * inv[mf];
            float* ap = attz + (size_t)(wrow + mf * 16 + fr) * 1024 + j0 + fk;
            const f32x4 o0 = {pr[0], pr[1], pr[2], pr[3]};
            const f32x4 o1 = {pr[4], pr[5], pr[6], pr[7]};
            __builtin_nontemporal_store(o0, (f32x4*)ap);        // gat_att: write-once stream
            __builtin_nontemporal_store(o1, (f32x4*)(ap + 4));
            union { unsigned u[4]; f16x8 v; } uh, ul;
            sp2(pr[0], pr[1], uh.u[0], ul.u[0]);
            sp2(pr[2], pr[3], uh.u[1], ul.u[1]);
            sp2(pr[4], pr[5], uh.u[2], ul.u[2]);
            sp2(pr[6], pr[7], uh.u[3], ul.u[3]);
            ph[mf] = uh.v; pl[mf] = ul.v;
        }
        #pragma unroll
        for (int nf = 0; nf < 4; ++nf) {
            const int off = p * BBUF + (nf * 16 + fr) * 32 + fk;
            const f16x8 bf = *(const f16x8*)(Bf_s + off);
            #pragma unroll
            for (int mf = 0; mf < 2; ++mf) {
                acc[mf][nf] = __builtin_amdgcn_mfma_f32_16x16x32_f16(ph[mf], bf, acc[mf][nf], 0, 0, 0);
                acc[mf][nf] = __builtin_amdgcn_mfma_f32_16x16x32_f16(pl[mf], bf, acc[mf][nf], 0, 0, 0);
            }
        }
        __syncthreads();
        p ^= 1;
    }
    #pragma unroll
    for (int mf = 0; mf < 2; ++mf) {
        #pragma unroll
        for (int i = 0; i < 4; ++i) {
            const int row_l = wrow + mf * 16 + g * 4 + i;
            const size_t base = ((size_t)bb * 1024 + row0 + row_l) * 256 + hh * 64 + fr;
            #pragma unroll
            for (int nf = 0; nf < 4; ++nf) {
                unsigned short hh16, ll16; sp1(acc[mf][nf][i], hh16, ll16);
                gouth[base + nf * 16] = hh16;
                goutl[base + nf * 16] = ll16;
            }
        }
    }
}

// ---------------------------------------------------------------------------
// PV with fused softmax + folded rstat + fused output projection. 3 blocks/CU.
// BM=32, BN=256, grid (32,1,16); A = P f16 pair, B = VT single f16.
// ---------------------------------------------------------------------------
__global__ __launch_bounds__(256, 3) void pv_k(
    float* __restrict__ scores, const float* __restrict__ pstats,
    const unsigned short* __restrict__ VTf,
    const unsigned short* __restrict__ WfcTf, const float* __restrict__ bfc,
    float* __restrict__ tout, float* __restrict__ outp)
{
    constexpr int ABUF = 32 * 32, BBUF = 256 * 32;
    __shared__ __align__(16) unsigned short SMp[4 * ABUF + 2 * BBUF];  // 40 KB
    unsigned short* const Ah_s = SMp;
    unsigned short* const Al_s = SMp + 2 * ABUF;
    unsigned short* const Bf_s = SMp + 4 * ABUF;

    int lin = blockIdx.x + 32 * blockIdx.z;
    lin = (lin & 7) * 64 + (lin >> 3);
    const int bx = lin & 31, z = lin >> 5;

    const int row0 = bx * 32;
    const int t = threadIdx.x, lane = t & 63, wid = t >> 6;
    const int fr = lane & 15, g = lane >> 4, fk = g * 8;
    const int rsub = lane >> 2, cbyt = (lane & 3) * 16;

    float* sc = scores + ((size_t)z * Lc + row0) * Lc;
    const unsigned short* VTf_z = VTf + (size_t)z * HDc * Lc;

    auto stageB = [&](int k0, int pp) {
        #pragma unroll
        for (int q = 0; q < 4; ++q) {
            const int r = q * 64 + wid * 16;
            const size_t gb = ((size_t)(r + rsub) * Lc + k0) * 2 + cbyt;
            gll16((const char*)VTf_z + gb, (char*)(Bf_s + pp * BBUF) + (size_t)r * 64);
        }
    };

    stageB(0, 0);

    const int ar = t >> 3, cq = (t & 7) * 4;
    float m_ = -1e30f, s_ = 0.f;
    {
        const int q = t & 7;
        const float* pb = pstats + (((size_t)z * 16 + q * 2) * Lc + row0 + ar) * 2;
        #pragma unroll
        for (int j = 0; j < 2; ++j) {
            const float2 pp = *(const float2*)(pb + (size_t)j * Lc * 2);
            const float nm = fmaxf(m_, pp.x);
            s_ = s_ * __expf(m_ - nm) + pp.y * __expf(pp.x - nm);
            m_ = nm;
        }
        #pragma unroll
        for (int ofs = 1; ofs < 8; ofs <<= 1) {
            const float om = __shfl_xor(m_, ofs, 64);
            const float os = __shfl_xor(s_, ofs, 64);
            const float nm = fmaxf(m_, om);
            s_ = s_ * __expf(m_ - nm) + os * __expf(om - nm);
            m_ = nm;
        }
    }
    const float iv_ = 1.0f / s_;

    auto stageA = [&](int k0, int pp) {
        float* srcS = sc + (size_t)ar * Lc + k0 + cq;
        const float4 v0 = *(const float4*)srcS;
        float pr[4];
        pr[0] = __expf(v0.x - m_) * iv_; pr[1] = __expf(v0.y - m_) * iv_;
        pr[2] = __expf(v0.z - m_) * iv_; pr[3] = __expf(v0.w - m_) * iv_;
        const f32x4 o = {pr[0], pr[1], pr[2], pr[3]};
        __builtin_nontemporal_store(o, (f32x4*)srcS);  // final t_att: write-once stream
        unsigned hu[2], lu[2];
        sp2(pr[0], pr[1], hu[0], lu[0]); sp2(pr[2], pr[3], hu[1], lu[1]);
        *(uint2*)(Ah_s + pp * ABUF + ar * 32 + cq) = make_uint2(hu[0], hu[1]);
        *(uint2*)(Al_s + pp * ABUF + ar * 32 + cq) = make_uint2(lu[0], lu[1]);
    };

    f32x4 acc[2][4] = {};
    stageA(0, 0);
    __syncthreads();
    int p = 0;
    for (int kt = 0; kt < 32; ++kt) {
        if (kt < 31) { stageB((kt + 1) * 32, p ^ 1); stageA((kt + 1) * 32, p ^ 1); }
        f16x8 ah[2], al[2];
        #pragma unroll
        for (int mf = 0; mf < 2; ++mf) {
            const int off = p * ABUF + (mf * 16 + fr) * 32 + fk;
            ah[mf] = *(const f16x8*)(Ah_s + off);
            al[mf] = *(const f16x8*)(Al_s + off);
        }
        #pragma unroll
        for (int nf = 0; nf < 4; ++nf) {
            const int off = p * BBUF + (wid * 64 + nf * 16 + fr) * 32 + fk;
            const f16x8 bf = *(const f16x8*)(Bf_s + off);
            #pragma unroll
            for (int mf = 0; mf < 2; ++mf) {
                acc[mf][nf] = __builtin_amdgcn_mfma_f32_16x16x32_f16(ah[mf], bf, acc[mf][nf], 0, 0, 0);
                acc[mf][nf] = __builtin_amdgcn_mfma_f32_16x16x32_f16(al[mf], bf, acc[mf][nf], 0, 0, 0);
            }
        }
        __syncthreads();
        p ^= 1;
    }

    // stash tile to LDS; then coalesced t_out write + fused out-projection
    constexpr int TS = 258;
    float* ts = (float*)SMp;
    #pragma unroll
    for (int mf = 0; mf < 2; ++mf)
        #pragma unroll
        for (int i = 0; i < 4; ++i) {
            const int rl = mf * 16 + g * 4 + i;
            #pragma unroll
            for (int nf = 0; nf < 4; ++nf)
                ts[rl * TS + wid * 64 + nf * 16 + fr] = acc[mf][nf][i];
        }
    __syncthreads();

    {   // t_out: linear nontemporal f32x4 from LDS tile (fully coalesced)
        const int row = t >> 3, c0 = (t & 7) * 32;
        float* dst = tout + ((size_t)z * Lc + row0 + row) * HDc + c0;
        const float* srcr = ts + row * TS + c0;
        #pragma unroll
        for (int j = 0; j < 8; ++j) {
            const f32x4 v = *(const f32x4*)(srcr + j * 4);
            __builtin_nontemporal_store(v, (f32x4*)(dst + j * 4));
        }
    }

    // out = t_out_tile @ WfcT^T + bfc  (K=256; each wave -> 16 out cols)
    const int ocol = wid * 16 + fr;
    f32x4 acc2[2] = {};
    #pragma unroll
    for (int kt2 = 0; kt2 < 8; ++kt2) {
        const int kk = kt2 * 32 + fk;
        const f16x8 bf = *(const f16x8*)(WfcTf + ocol * 256 + kk);
        #pragma unroll
        for (int mf = 0; mf < 2; ++mf) {
            const float* ap = ts + (mf * 16 + fr) * TS + kk;
            union { unsigned u[4]; f16x8 v; } ahh, all_;
            sp2(ap[0], ap[1], ahh.u[0], all_.u[0]);
            sp2(ap[2], ap[3], ahh.u[1], all_.u[1]);
            sp2(ap[4], ap[5], ahh.u[2], all_.u[2]);
            sp2(ap[6], ap[7], ahh.u[3], all_.u[3]);
            acc2[mf] = __builtin_amdgcn_mfma_f32_16x16x32_f16(ahh.v, bf, acc2[mf], 0, 0, 0);
            acc2[mf] = __builtin_amdgcn_mfma_f32_16x16x32_f16(all_.v, bf, acc2[mf], 0, 0, 0);
        }
    }
    const float bo = bfc[ocol];
    #pragma unroll
    for (int mf = 0; mf < 2; ++mf)
        #pragma unroll
        for (int i = 0; i < 4; ++i)
            __builtin_nontemporal_store(acc2[mf][i] + bo,
                outp + ((size_t)z * Lc + row0 + mf * 16 + g * 4 + i) * Dc + ocol);
}

// 32x32 transpose + single-f16 convert helper
__device__ __forceinline__ void tr32(const float* src, unsigned short* dh,
                                     int R, int C, int r0, int c0,
                                     float (*tile)[33], int t)
{
    const int tc = t & 31, tr = t >> 5;
    #pragma unroll
    for (int rr = 0; rr < 32; rr += 8)
        tile[tr + rr][tc] = src[(size_t)(r0 + tr + rr) * C + c0 + tc];
    __syncthreads();
    #pragma unroll
    for (int rr = 0; rr < 32; rr += 8) {
        const size_t o = (size_t)(c0 + tr + rr) * R + r0 + tc;
        dh[o] = cv1(tile[tc][tr + rr]);
    }
}

// all weight transposes (single f16) + bias concat in one launch
__global__ __launch_bounds__(256) void prep_k(
    const float* __restrict__ W, const float* __restrict__ Wq,
    const float* __restrict__ Wk, const float* __restrict__ Wv,
    const float* __restrict__ Wfc, const float* __restrict__ bq,
    const float* __restrict__ bk, const float* __restrict__ bv,
    unsigned short* __restrict__ WTf, unsigned short* __restrict__ Wcf,
    unsigned short* __restrict__ WfcTf, float* __restrict__ bcat)
{
    __shared__ float tile[32][33];
    const int bx = blockIdx.x, by = blockIdx.y, t = threadIdx.x;
    if (by == 0) {
        if (bx >= 32) return;
        const int h = bx >> 3, tl = bx & 7;
        tr32(W + (size_t)h * Fc * Dc, WTf + (size_t)h * Dc * Fc,
             Fc, Dc, (tl >> 1) * 32, (tl & 1) * 32, tile, t);
    } else if (by <= 3) {
        const float* s = (by == 1) ? Wq : (by == 2) ? Wk : Wv;
        const size_t off = (size_t)(by - 1) * HDc * HDc;
        tr32(s, Wcf + off, HDc, HDc, (bx >> 3) * 32, (bx & 7) * 32, tile, t);
    } else {
        if (bx < 16) {
            tr32(Wfc, WfcTf, HDc, Dc, (bx >> 1) * 32, (bx & 1) * 32, tile, t);
        } else if (bx == 16) {
            bcat[t] = bq[t]; bcat[256 + t] = bk[t]; bcat[512 + t] = bv[t];
        }
    }
}

extern "C" void kernel_launch(void* const* d_in, const int* in_sizes, int n_in,
                              void* d_out, int out_size, void* d_ws, size_t ws_size,
                              hipStream_t stream)
{
    const float* x   = (const float*)d_in[0];
    const float* W   = (const float*)d_in[1];
    const float* a1  = (const float*)d_in[2];
    const float* a2  = (const float*)d_in[3];
    const float* Wq  = (const float*)d_in[4];
    const float* bq  = (const float*)d_in[5];
    const float* Wk  = (const float*)d_in[6];
    const float* bk  = (const float*)d_in[7];
    const float* Wv  = (const float*)d_in[8];
    const float* bv  = (const float*)d_in[9];
    const float* Wfc = (const float*)d_in[10];
    const float* bfc = (const float*)d_in[11];

    float* outp    = (float*)d_out;
    float* gat_att = outp + (size_t)Bc * Lc * Dc;
    float* t_att   = gat_att + (size_t)Hc * Bc * Lc * Lc;
    float* t_out   = t_att + (size_t)Bc * Lc * Lc;

    constexpr size_t MB = 1024 * 1024;
    char* wsb = (char*)d_ws;
    unsigned short* WhTf = (unsigned short*)wsb;          // 0-8MB, -> VT f16
    unsigned short* VTf  = WhTf;
    unsigned short* gouth = (unsigned short*)(wsb + 8 * MB);   // 8-24MB
    unsigned short* goutl = gouth + (size_t)Nrows * HDc;
    unsigned short* Qh = (unsigned short*)(wsb + 24 * MB);     // 24-40MB
    unsigned short* Ql = Qh + (size_t)Nrows * HDc;
    unsigned short* Kf = (unsigned short*)(wsb + 40 * MB);     // 40-48MB
    float* si  = (float*)(wsb + 48 * MB);
    float* sj  = si + Hc * Nrows;
    float* pstats = sj + Hc * Nrows;                           // [16][16][1024][2]
    unsigned short* WTf = (unsigned short*)(pstats + (size_t)Bc * 16 * Lc * 2);
    unsigned short* Wcf = WTf + Hc * Dc * Fc;                  // [768][256]
    unsigned short* WfcTf = Wcf + 768 * HDc;                   // [64][256]
    float* bcat = (float*)(WfcTf + Dc * HDc);                  // [768]

    const dim3 blk(256);

    // 0. weight prep
    prep_k<<<dim3(64, 5), blk, 0, stream>>>(W, Wq, Wk, Wv, Wfc, bq, bk, bv,
        WTf, Wcf, WfcTf, bcat);

    // 1. WhT f16 = (x @ W[h]^T)^T + fused si/sj
    mm_k<128, 64, A_F32, E_WHT><<<dim3(Nrows / 128, 1, Hc), blk, 0, stream>>>(
        x, nullptr, nullptr, WTf, nullptr, nullptr,
        WhTf, nullptr, nullptr, nullptr,
        Fc, Fc, Fc, 0, 0LL, (long long)Dc * Fc, 0LL, 1.f, a1, a2, si, sj, nullptr);

    // 2. fused GAT: gat_att + gout f16 pair
    gat_k<<<dim3(Lc / 128, 1, 64), blk, 0, stream>>>(si, sj,
        WhTf, gat_att, gouth, goutl);

    // 3. fused QKV projection
    mm_k<128, 128, A_HL, E_QKV><<<dim3(6, Nrows / 128, 1), blk, 0, stream>>>(
        nullptr, gouth, goutl, Wcf, bcat, nullptr,
        Qh, Ql, Kf, VTf,
        HDc, HDc, HDc, HDc, 0LL, 0LL, 0LL, 1.f, nullptr, nullptr, nullptr, nullptr, nullptr);

    // 4. raw scaled scores + partial row stats
    mm_k<128, 128, A_HL, E_STATS><<<dim3(8, 8, Bc), blk, 0, stream>>>(
        nullptr, Qh, Ql, Kf, nullptr, t_att,
        nullptr, nullptr, nullptr, nullptr,
        HDc, HDc, HDc, Lc, (long long)Lc * HDc, (long long)Lc * HDc,
        (long long)Lc * Lc, 0.0625f, nullptr, nullptr, nullptr, nullptr, pstats);

    // 5. PV: folded rstat + fused softmax + t_out + fused out-projection
    pv_k<<<dim3(32, 1, Bc), blk, 0, stream>>>(t_att, pstats, VTf,
        WfcTf, bfc, t_out, outp);
}

// Round 11
// 201.597 us; speedup vs baseline: 1.5519x; 1.5519x over previous
//
#include <hip/hip_runtime.h>

// TemporalGAT on MI355X — round 11: revert round-10 regression (nontemporal
// stores + occupancy bumps) back to round-9 structure; keep only the coalesced
// t_out write from LDS tile (plain stores). f16 2-term split MFMA.
// B=16, L=1024, F=128, H=4, D=64, HD=256, N=B*L=16384

constexpr int Bc = 16, Lc = 1024, Fc = 128, Hc = 4, Dc = 64, HDc = 256;
constexpr int Nrows = Bc * Lc;  // 16384
#define ALPHA_SLOPE 0.2f

typedef __attribute__((ext_vector_type(8))) _Float16 f16x8;
typedef __attribute__((ext_vector_type(4))) float f32x4;

enum { A_F32 = 0, A_HL = 1 };
enum { E_WHT = 2, E_STATS = 3, E_QKV = 4 };

__device__ __forceinline__ float lrelu(float x) { return x > 0.f ? x : ALPHA_SLOPE * x; }

__device__ __forceinline__ void gll16(const void* g, void* l) {
    __builtin_amdgcn_global_load_lds(
        (const __attribute__((address_space(1))) void*)g,
        (__attribute__((address_space(3))) void*)l, 16, 0, 0);
}

// f32 -> f16 conversions. A-operands: 2-term split; B-operands: single f16.
__device__ __forceinline__ unsigned short cv1(float v) {
    union { _Float16 f; unsigned short u; } c; c.f = (_Float16)v; return c.u;
}
__device__ __forceinline__ void sp2(float a, float b, unsigned& h, unsigned& l) {
    const _Float16 ha = (_Float16)a, hb = (_Float16)b;
    union { _Float16 f[2]; unsigned u; } H, L;
    H.f[0] = ha; H.f[1] = hb;
    L.f[0] = (_Float16)(a - (float)ha);
    L.f[1] = (_Float16)(b - (float)hb);
    h = H.u; l = L.u;
}
__device__ __forceinline__ void sp1(float v, unsigned short& h, unsigned short& l) {
    const _Float16 hv = (_Float16)v;
    union { _Float16 f; unsigned short u; } H, L;
    H.f = hv; L.f = (_Float16)(v - (float)hv);
    h = H.u; l = L.u;
}

// ---------------------------------------------------------------------------
// MFMA GEMM, 2-phase double-buffered, XCD-swizzled: C = A[M,K] @ Bt[N,K]^T.
// A = f16 pair (or f32 reg-converted); B = single f16.
// ---------------------------------------------------------------------------
template <int BM, int BN, int AMODE, int EPI>
__global__ __launch_bounds__(256, 2) void mm_k(
    const float* __restrict__ Af,
    const unsigned short* __restrict__ Agh, const unsigned short* __restrict__ Agl,
    const unsigned short* __restrict__ Bg,
    const float* __restrict__ bias,
    float* __restrict__ Cf,
    unsigned short* __restrict__ Ch, unsigned short* __restrict__ Cl,
    unsigned short* __restrict__ Ch2, unsigned short* __restrict__ Ch3,
    int K, int lda, int ldb, int ldc,
    long long zA, long long zB, long long zC, float alpha,
    const float* __restrict__ a1, const float* __restrict__ a2,
    float* __restrict__ si, float* __restrict__ sj, float* __restrict__ pstats)
{
    constexpr int ABUF = BM * 32, BBUF = BN * 32;
    __shared__ __align__(16) unsigned short SM[4 * ABUF + 2 * BBUF];
    unsigned short* const Ah_s = SM;
    unsigned short* const Al_s = SM + 2 * ABUF;
    unsigned short* const Bf_s = SM + 4 * ABUF;

    constexpr bool SWAPXY = (EPI == E_QKV);

    const int nbx = gridDim.x, nby = gridDim.y;
    int lin = blockIdx.x + nbx * (blockIdx.y + nby * blockIdx.z);
    const int ntot = nbx * nby * gridDim.z;
    lin = (lin & 7) * (ntot >> 3) + (lin >> 3);
    const int bx = lin % nbx;
    const int rem = lin / nbx;
    const int by = rem % nby;
    const int z  = rem / nby;

    if (AMODE == A_F32) { Af += (size_t)z * zA; }
    else { Agh += (size_t)z * zA; Agl += (size_t)z * zA; }
    Bg += (size_t)z * zB;
    if (Cf) Cf += (size_t)z * zC;

    constexpr int WC = (BN == 64) ? 1 : 2, WR = 4 / WC;
    constexpr int WM = BM / WR, WN = BN / WC, MF = WM / 16, NF = WN / 16;
    const int row0 = (SWAPXY ? by : bx) * BM;
    const int col0 = (SWAPXY ? bx : by) * BN;
    const int t = threadIdx.x, lane = t & 63, wid = t >> 6;
    const int fr = lane & 15, g = lane >> 4, fk = g * 8;
    const int wrow = (wid / WC) * WM, wcol = (wid % WC) * WN;
    const int rsub = lane >> 2, cbyt = (lane & 3) * 16;

    f32x4 acc[MF][NF] = {};

    auto stageB = [&](int k0, int pp) {
        #pragma unroll
        for (int q = 0; q < BN / 64; ++q) {
            const int r = wid * (BN / 4) + q * 16;
            const size_t gb = ((size_t)(col0 + r + rsub) * ldb + k0) * 2 + cbyt;
            gll16((const char*)Bg + gb, (char*)(Bf_s + pp * BBUF) + (size_t)r * 64);
        }
    };
    auto stageA = [&](int k0, int pp) {
        if (AMODE == A_HL) {
            #pragma unroll
            for (int q = 0; q < BM / 64; ++q) {
                const int r = wid * (BM / 4) + q * 16;
                const size_t gb = ((size_t)(row0 + r + rsub) * lda + k0) * 2 + cbyt;
                gll16((const char*)Agh + gb, (char*)(Ah_s + pp * ABUF) + (size_t)r * 64);
                gll16((const char*)Agl + gb, (char*)(Al_s + pp * ABUF) + (size_t)r * 64);
            }
        } else {
            const int r = t >> 1, h2 = t & 1;
            const float* srcA = Af + (size_t)(row0 + r) * lda + k0 + h2 * 16;
            const float4 v0 = ((const float4*)srcA)[0];
            const float4 v1 = ((const float4*)srcA)[1];
            const float4 v2 = ((const float4*)srcA)[2];
            const float4 v3 = ((const float4*)srcA)[3];
            unsigned hu[8], lu[8];
            sp2(v0.x, v0.y, hu[0], lu[0]); sp2(v0.z, v0.w, hu[1], lu[1]);
            sp2(v1.x, v1.y, hu[2], lu[2]); sp2(v1.z, v1.w, hu[3], lu[3]);
            sp2(v2.x, v2.y, hu[4], lu[4]); sp2(v2.z, v2.w, hu[5], lu[5]);
            sp2(v3.x, v3.y, hu[6], lu[6]); sp2(v3.z, v3.w, hu[7], lu[7]);
            uint4* dh = (uint4*)(Ah_s + pp * ABUF + r * 32 + h2 * 16);
            dh[0] = make_uint4(hu[0], hu[1], hu[2], hu[3]);
            dh[1] = make_uint4(hu[4], hu[5], hu[6], hu[7]);
            uint4* dl = (uint4*)(Al_s + pp * ABUF + r * 32 + h2 * 16);
            dl[0] = make_uint4(lu[0], lu[1], lu[2], lu[3]);
            dl[1] = make_uint4(lu[4], lu[5], lu[6], lu[7]);
        }
    };

    stageB(0, 0);
    stageA(0, 0);
    __syncthreads();

    const int NT = K / 32;
    int p = 0;
    for (int kt = 0; kt < NT; ++kt) {
        if (kt + 1 < NT) { stageB((kt + 1) * 32, p ^ 1); stageA((kt + 1) * 32, p ^ 1); }
        f16x8 ah[MF], al[MF];
        #pragma unroll
        for (int mf = 0; mf < MF; ++mf) {
            const int off = p * ABUF + (wrow + mf * 16 + fr) * 32 + fk;
            ah[mf] = *(const f16x8*)(Ah_s + off);
            al[mf] = *(const f16x8*)(Al_s + off);
        }
        #pragma unroll
        for (int nf = 0; nf < NF; ++nf) {
            const int off = p * BBUF + (wcol + nf * 16 + fr) * 32 + fk;
            const f16x8 bf = *(const f16x8*)(Bf_s + off);
            #pragma unroll
            for (int mf = 0; mf < MF; ++mf) {
                acc[mf][nf] = __builtin_amdgcn_mfma_f32_16x16x32_f16(ah[mf], bf, acc[mf][nf], 0, 0, 0);
                acc[mf][nf] = __builtin_amdgcn_mfma_f32_16x16x32_f16(al[mf], bf, acc[mf][nf], 0, 0, 0);
            }
        }
        __syncthreads();
        p ^= 1;
    }

    // ---- epilogues (C/D layout: col = lane&15, row = (lane>>4)*4 + i [m89])
    float* ts = (float*)SM;

    if (EPI == E_STATS) {
        #pragma unroll
        for (int mf = 0; mf < MF; ++mf) {
            #pragma unroll
            for (int i = 0; i < 4; ++i) {
                const size_t row = (size_t)row0 + wrow + mf * 16 + g * 4 + i;
                const size_t co = row * ldc + col0 + wcol + fr;
                #pragma unroll
                for (int nf = 0; nf < NF; ++nf) {
                    float v = acc[mf][nf][i] * alpha;
                    acc[mf][nf][i] = v;
                    Cf[co + nf * 16] = v;
                }
            }
        }
        const int ty = by * WC + (wid % WC);
        #pragma unroll
        for (int mf = 0; mf < MF; ++mf) {
            #pragma unroll
            for (int i = 0; i < 4; ++i) {
                float m = acc[mf][0][i], s;
                #pragma unroll
                for (int nf = 1; nf < NF; ++nf) m = fmaxf(m, acc[mf][nf][i]);
                s = 0.f;
                #pragma unroll
                for (int nf = 0; nf < NF; ++nf) s += __expf(acc[mf][nf][i] - m);
                #pragma unroll
                for (int ofs = 1; ofs < 16; ofs <<= 1) {
                    const float om = __shfl_xor(m, ofs, 64);
                    const float os = __shfl_xor(s, ofs, 64);
                    const float nm = fmaxf(m, om);
                    s = s * __expf(m - nm) + os * __expf(om - nm);
                    m = nm;
                }
                if (fr == 0) {
                    const size_t row = (size_t)row0 + wrow + mf * 16 + g * 4 + i;
                    float* pp = pstats + (((size_t)z * 16 + ty) * Lc + row) * 2;
                    pp[0] = m; pp[1] = s;
                }
            }
        }
    }

    if (EPI == E_QKV) {
        float bv_[NF];
        #pragma unroll
        for (int nf = 0; nf < NF; ++nf) bv_[nf] = bias[col0 + wcol + nf * 16 + fr];
        #pragma unroll
        for (int mf = 0; mf < MF; ++mf)
            #pragma unroll
            for (int i = 0; i < 4; ++i)
                #pragma unroll
                for (int nf = 0; nf < NF; ++nf) acc[mf][nf][i] += bv_[nf];

        if (col0 < 256) {
            // Q: f16 pair write (A-operand of QK)
            #pragma unroll
            for (int mf = 0; mf < MF; ++mf) {
                #pragma unroll
                for (int i = 0; i < 4; ++i) {
                    const size_t row = (size_t)row0 + wrow + mf * 16 + g * 4 + i;
                    const size_t co = row * ldc + col0 + wcol + fr;
                    #pragma unroll
                    for (int nf = 0; nf < NF; ++nf) {
                        unsigned short hh16, ll16; sp1(acc[mf][nf][i], hh16, ll16);
                        Ch[co + nf * 16] = hh16; Cl[co + nf * 16] = ll16;
                    }
                }
            }
        } else if (col0 < 512) {
            // K: single f16 write (B-operand of QK)
            const int cl0 = col0 & 255;
            #pragma unroll
            for (int mf = 0; mf < MF; ++mf) {
                #pragma unroll
                for (int i = 0; i < 4; ++i) {
                    const size_t row = (size_t)row0 + wrow + mf * 16 + g * 4 + i;
                    const size_t co = row * ldc + cl0 + wcol + fr;
                    #pragma unroll
                    for (int nf = 0; nf < NF; ++nf)
                        Ch2[co + nf * 16] = cv1(acc[mf][nf][i]);
                }
            }
        } else {
            // V: transposed single-f16 write -> VT[b][d][l]
            const int bq_ = row0 >> 10, lg0 = row0 & 1023;
            #pragma unroll
            for (int hf = 0; hf < 2; ++hf) {
                if ((wid & 1) == hf) {
                    #pragma unroll
                    for (int mf = 0; mf < MF; ++mf)
                        #pragma unroll
                        for (int i = 0; i < 4; ++i) {
                            const int rr = wrow + mf * 16 + g * 4 + i;
                            #pragma unroll
                            for (int nf = 0; nf < NF; ++nf)
                                ts[rr * 65 + nf * 16 + fr] = acc[mf][nf][i];
                        }
                }
                __syncthreads();
                const int l = t & 127, db = (t >> 7) * 32;
                #pragma unroll
                for (int dd = 0; dd < 32; ++dd) {
                    const int dl = db + dd;
                    const size_t o = ((size_t)bq_ * 256 + (col0 - 512) + hf * 64 + dl) * 1024 + lg0 + l;
                    Ch3[o] = cv1(ts[l * 65 + dl]);
                }
                __syncthreads();
            }
        }
    }

    if (EPI == E_WHT) {
        float a1v[NF], a2v[NF];
        #pragma unroll
        for (int nf = 0; nf < NF; ++nf) {
            a1v[nf] = a1[(size_t)z * Dc + nf * 16 + fr];
            a2v[nf] = a2[(size_t)z * Dc + nf * 16 + fr];
        }
        #pragma unroll
        for (int mf = 0; mf < MF; ++mf) {
            #pragma unroll
            for (int i = 0; i < 4; ++i) {
                float p1 = 0.f, p2 = 0.f;
                #pragma unroll
                for (int nf = 0; nf < NF; ++nf) {
                    p1 = fmaf(acc[mf][nf][i], a1v[nf], p1);
                    p2 = fmaf(acc[mf][nf][i], a2v[nf], p2);
                }
                #pragma unroll
                for (int ofs = 1; ofs < 16; ofs <<= 1) {
                    p1 += __shfl_xor(p1, ofs, 64);
                    p2 += __shfl_xor(p2, ofs, 64);
                }
                if (fr == 0) {
                    const int row = row0 + wrow + mf * 16 + g * 4 + i;
                    si[(size_t)z * Nrows + row] = p1;
                    sj[(size_t)z * Nrows + row] = p2;
                }
            }
        }
        #pragma unroll
        for (int mf = 0; mf < MF; ++mf)
            #pragma unroll
            for (int i = 0; i < 4; ++i) {
                const int rr = wrow + mf * 16 + g * 4 + i;
                #pragma unroll
                for (int nf = 0; nf < NF; ++nf)
                    ts[rr * 65 + nf * 16 + fr] = acc[mf][nf][i];
            }
        __syncthreads();
        const int bq_ = row0 >> 10, lg0 = row0 & 1023;
        const int l = t & 127, db = (t >> 7) * 32;
        #pragma unroll
        for (int dd = 0; dd < 32; ++dd) {
            const int d = db + dd;
            const size_t o = (((size_t)(z * 16 + bq_)) * 64 + d) * 1024 + lg0 + l;
            Ch[o] = cv1(ts[l * 65 + d]);
        }
    }
}

// ---------------------------------------------------------------------------
// Fused GAT, 2-phase, swizzled, in-block softmax stats. 3 blocks/CU (round-9).
// ---------------------------------------------------------------------------
__global__ __launch_bounds__(256, 3) void gat_k(
    const float* __restrict__ si, const float* __restrict__ sj,
    const unsigned short* __restrict__ WhTf,
    float* __restrict__ att, unsigned short* __restrict__ gouth,
    unsigned short* __restrict__ goutl)
{
    constexpr int BBUF = 64 * 32;
    __shared__ __align__(16) unsigned short SMg[2 * BBUF];
    __shared__ __align__(16) float sjs[Lc];
    __shared__ float redm[4];
    unsigned short* const Bf_s = SMg;

    int lin = blockIdx.x + 8 * blockIdx.z;
    lin = (lin & 7) * 64 + (lin >> 3);
    const int bx = lin & 7, z = lin >> 3;

    const int row0 = bx * 128;
    const int t = threadIdx.x, lane = t & 63, wid = t >> 6;
    const int fr = lane & 15, g = lane >> 4, fk = g * 8;
    const int wrow = wid * 32;
    const int hh = z >> 4, bb = z & 15;
    const int rsub = lane >> 2, cbyt = (lane & 3) * 16;

    const unsigned short* WhTf_z = WhTf + (size_t)z * 64 * 1024;
    const float* sjz = sj + (size_t)z * 1024;
    float* attz = att + ((size_t)z * 1024 + row0) * 1024;

    auto stageB = [&](int j0, int pp) {
        const int r = wid * 16;
        const size_t gb = ((size_t)(r + rsub) * 1024 + j0) * 2 + cbyt;
        gll16((const char*)WhTf_z + gb, (char*)(Bf_s + pp * BBUF) + (size_t)r * 64);
    };

    stageB(0, 0);
    ((float4*)sjs)[t] = ((const float4*)sjz)[t];
    __syncthreads();

    {
        const float4 v = ((const float4*)sjs)[t];
        float m4 = fmaxf(fmaxf(v.x, v.y), fmaxf(v.z, v.w));
        #pragma unroll
        for (int ofs = 32; ofs >= 1; ofs >>= 1) m4 = fmaxf(m4, __shfl_xor(m4, ofs, 64));
        if (lane == 0) redm[wid] = m4;
    }
    __syncthreads();
    const float smax = fmaxf(fmaxf(redm[0], redm[1]), fmaxf(redm[2], redm[3]));

    float siv[2], mr[2], inv[2];
    #pragma unroll
    for (int mf = 0; mf < 2; ++mf) {
        const int r = row0 + wrow + mf * 16 + fr;
        const float sv = si[(size_t)hh * Nrows + bb * 1024 + r];
        siv[mf] = sv;
        mr[mf] = lrelu(sv + smax);
        float s = 0.f;
        const float4* sp = (const float4*)sjs + g * 64;
        #pragma unroll 4
        for (int c = 0; c < 64; ++c) {
            const float4 w = sp[c];
            s += __expf(lrelu(sv + w.x) - mr[mf]) + __expf(lrelu(sv + w.y) - mr[mf])
               + __expf(lrelu(sv + w.z) - mr[mf]) + __expf(lrelu(sv + w.w) - mr[mf]);
        }
        s += __shfl_xor(s, 16, 64);
        s += __shfl_xor(s, 32, 64);
        inv[mf] = 1.0f / s;
    }

    f32x4 acc[2][4] = {};
    int p = 0;
    for (int kt = 0; kt < 32; ++kt) {
        const int j0 = kt * 32;
        if (kt < 31) stageB(j0 + 32, p ^ 1);
        f16x8 ph[2], pl[2];
        #pragma unroll
        for (int mf = 0; mf < 2; ++mf) {
            const float4 s0 = ((const float4*)sjs)[(j0 >> 2) + g * 2];
            const float4 s1 = ((const float4*)sjs)[(j0 >> 2) + g * 2 + 1];
            float pr[8];
            pr[0] = __expf(lrelu(siv[mf] + s0.x) - mr[mf]) * inv[mf];
            pr[1] = __expf(lrelu(siv[mf] + s0.y) - mr[mf]) * inv[mf];
            pr[2] = __expf(lrelu(siv[mf] + s0.z) - mr[mf]) * inv[mf];
            pr[3] = __expf(lrelu(siv[mf] + s0.w) - mr[mf]) * inv[mf];
            pr[4] = __expf(lrelu(siv[mf] + s1.x) - mr[mf]) * inv[mf];
            pr[5] = __expf(lrelu(siv[mf] + s1.y) - mr[mf]) * inv[mf];
            pr[6] = __expf(lrelu(siv[mf] + s1.z) - mr[mf]) * inv[mf];
            pr[7] = __expf(lrelu(siv[mf] + s1.w) - mr[mf]) * inv[mf];
            float* ap = attz + (size_t)(wrow + mf * 16 + fr) * 1024 + j0 + fk;
            *(float4*)ap       = make_float4(pr[0], pr[1], pr[2], pr[3]);
            *(float4*)(ap + 4) = make_float4(pr[4], pr[5], pr[6], pr[7]);
            union { unsigned u[4]; f16x8 v; } uh, ul;
            sp2(pr[0], pr[1], uh.u[0], ul.u[0]);
            sp2(pr[2], pr[3], uh.u[1], ul.u[1]);
            sp2(pr[4], pr[5], uh.u[2], ul.u[2]);
            sp2(pr[6], pr[7], uh.u[3], ul.u[3]);
            ph[mf] = uh.v; pl[mf] = ul.v;
        }
        #pragma unroll
        for (int nf = 0; nf < 4; ++nf) {
            const int off = p * BBUF + (nf * 16 + fr) * 32 + fk;
            const f16x8 bf = *(const f16x8*)(Bf_s + off);
            #pragma unroll
            for (int mf = 0; mf < 2; ++mf) {
                acc[mf][nf] = __builtin_amdgcn_mfma_f32_16x16x32_f16(ph[mf], bf, acc[mf][nf], 0, 0, 0);
                acc[mf][nf] = __builtin_amdgcn_mfma_f32_16x16x32_f16(pl[mf], bf, acc[mf][nf], 0, 0, 0);
            }
        }
        __syncthreads();
        p ^= 1;
    }
    #pragma unroll
    for (int mf = 0; mf < 2; ++mf) {
        #pragma unroll
        for (int i = 0; i < 4; ++i) {
            const int row_l = wrow + mf * 16 + g * 4 + i;
            const size_t base = ((size_t)bb * 1024 + row0 + row_l) * 256 + hh * 64 + fr;
            #pragma unroll
            for (int nf = 0; nf < 4; ++nf) {
                unsigned short hh16, ll16; sp1(acc[mf][nf][i], hh16, ll16);
                gouth[base + nf * 16] = hh16;
                goutl[base + nf * 16] = ll16;
            }
        }
    }
}

// ---------------------------------------------------------------------------
// PV with fused softmax + folded rstat + fused output projection. 2 blocks/CU.
// BM=32, BN=256, grid (32,1,16); A = P f16 pair, B = VT single f16.
// t_out written coalesced from the LDS tile (plain stores).
// ---------------------------------------------------------------------------
__global__ __launch_bounds__(256, 2) void pv_k(
    float* __restrict__ scores, const float* __restrict__ pstats,
    const unsigned short* __restrict__ VTf,
    const unsigned short* __restrict__ WfcTf, const float* __restrict__ bfc,
    float* __restrict__ tout, float* __restrict__ outp)
{
    constexpr int ABUF = 32 * 32, BBUF = 256 * 32;
    __shared__ __align__(16) unsigned short SMp[4 * ABUF + 2 * BBUF];  // 40 KB
    unsigned short* const Ah_s = SMp;
    unsigned short* const Al_s = SMp + 2 * ABUF;
    unsigned short* const Bf_s = SMp + 4 * ABUF;

    int lin = blockIdx.x + 32 * blockIdx.z;
    lin = (lin & 7) * 64 + (lin >> 3);
    const int bx = lin & 31, z = lin >> 5;

    const int row0 = bx * 32;
    const int t = threadIdx.x, lane = t & 63, wid = t >> 6;
    const int fr = lane & 15, g = lane >> 4, fk = g * 8;
    const int rsub = lane >> 2, cbyt = (lane & 3) * 16;

    float* sc = scores + ((size_t)z * Lc + row0) * Lc;
    const unsigned short* VTf_z = VTf + (size_t)z * HDc * Lc;

    auto stageB = [&](int k0, int pp) {
        #pragma unroll
        for (int q = 0; q < 4; ++q) {
            const int r = q * 64 + wid * 16;
            const size_t gb = ((size_t)(r + rsub) * Lc + k0) * 2 + cbyt;
            gll16((const char*)VTf_z + gb, (char*)(Bf_s + pp * BBUF) + (size_t)r * 64);
        }
    };

    stageB(0, 0);

    const int ar = t >> 3, cq = (t & 7) * 4;
    float m_ = -1e30f, s_ = 0.f;
    {
        const int q = t & 7;
        const float* pb = pstats + (((size_t)z * 16 + q * 2) * Lc + row0 + ar) * 2;
        #pragma unroll
        for (int j = 0; j < 2; ++j) {
            const float2 pp = *(const float2*)(pb + (size_t)j * Lc * 2);
            const float nm = fmaxf(m_, pp.x);
            s_ = s_ * __expf(m_ - nm) + pp.y * __expf(pp.x - nm);
            m_ = nm;
        }
        #pragma unroll
        for (int ofs = 1; ofs < 8; ofs <<= 1) {
            const float om = __shfl_xor(m_, ofs, 64);
            const float os = __shfl_xor(s_, ofs, 64);
            const float nm = fmaxf(m_, om);
            s_ = s_ * __expf(m_ - nm) + os * __expf(om - nm);
            m_ = nm;
        }
    }
    const float iv_ = 1.0f / s_;

    auto stageA = [&](int k0, int pp) {
        float* srcS = sc + (size_t)ar * Lc + k0 + cq;
        const float4 v0 = *(const float4*)srcS;
        float pr[4];
        pr[0] = __expf(v0.x - m_) * iv_; pr[1] = __expf(v0.y - m_) * iv_;
        pr[2] = __expf(v0.z - m_) * iv_; pr[3] = __expf(v0.w - m_) * iv_;
        *(float4*)srcS = make_float4(pr[0], pr[1], pr[2], pr[3]);
        unsigned hu[2], lu[2];
        sp2(pr[0], pr[1], hu[0], lu[0]); sp2(pr[2], pr[3], hu[1], lu[1]);
        *(uint2*)(Ah_s + pp * ABUF + ar * 32 + cq) = make_uint2(hu[0], hu[1]);
        *(uint2*)(Al_s + pp * ABUF + ar * 32 + cq) = make_uint2(lu[0], lu[1]);
    };

    f32x4 acc[2][4] = {};
    stageA(0, 0);
    __syncthreads();
    int p = 0;
    for (int kt = 0; kt < 32; ++kt) {
        if (kt < 31) { stageB((kt + 1) * 32, p ^ 1); stageA((kt + 1) * 32, p ^ 1); }
        f16x8 ah[2], al[2];
        #pragma unroll
        for (int mf = 0; mf < 2; ++mf) {
            const int off = p * ABUF + (mf * 16 + fr) * 32 + fk;
            ah[mf] = *(const f16x8*)(Ah_s + off);
            al[mf] = *(const f16x8*)(Al_s + off);
        }
        #pragma unroll
        for (int nf = 0; nf < 4; ++nf) {
            const int off = p * BBUF + (wid * 64 + nf * 16 + fr) * 32 + fk;
            const f16x8 bf = *(const f16x8*)(Bf_s + off);
            #pragma unroll
            for (int mf = 0; mf < 2; ++mf) {
                acc[mf][nf] = __builtin_amdgcn_mfma_f32_16x16x32_f16(ah[mf], bf, acc[mf][nf], 0, 0, 0);
                acc[mf][nf] = __builtin_amdgcn_mfma_f32_16x16x32_f16(al[mf], bf, acc[mf][nf], 0, 0, 0);
            }
        }
        __syncthreads();
        p ^= 1;
    }

    // stash tile to LDS; then coalesced t_out write + fused out-projection
    constexpr int TS = 258;
    float* ts = (float*)SMp;
    #pragma unroll
    for (int mf = 0; mf < 2; ++mf)
        #pragma unroll
        for (int i = 0; i < 4; ++i) {
            const int rl = mf * 16 + g * 4 + i;
            #pragma unroll
            for (int nf = 0; nf < 4; ++nf)
                ts[rl * TS + wid * 64 + nf * 16 + fr] = acc[mf][nf][i];
        }
    __syncthreads();

    {   // t_out: linear f32x4 writes from LDS tile (fully coalesced)
        const int row = t >> 3, c0 = (t & 7) * 32;
        float* dst = tout + ((size_t)z * Lc + row0 + row) * HDc + c0;
        const float* srcr = ts + row * TS + c0;
        #pragma unroll
        for (int j = 0; j < 8; ++j)
            *(f32x4*)(dst + j * 4) = *(const f32x4*)(srcr + j * 4);
    }

    // out = t_out_tile @ WfcT^T + bfc  (K=256; each wave -> 16 out cols)
    const int ocol = wid * 16 + fr;
    f32x4 acc2[2] = {};
    #pragma unroll
    for (int kt2 = 0; kt2 < 8; ++kt2) {
        const int kk = kt2 * 32 + fk;
        const f16x8 bf = *(const f16x8*)(WfcTf + ocol * 256 + kk);
        #pragma unroll
        for (int mf = 0; mf < 2; ++mf) {
            const float* ap = ts + (mf * 16 + fr) * TS + kk;
            union { unsigned u[4]; f16x8 v; } ahh, all_;
            sp2(ap[0], ap[1], ahh.u[0], all_.u[0]);
            sp2(ap[2], ap[3], ahh.u[1], all_.u[1]);
            sp2(ap[4], ap[5], ahh.u[2], all_.u[2]);
            sp2(ap[6], ap[7], ahh.u[3], all_.u[3]);
            acc2[mf] = __builtin_amdgcn_mfma_f32_16x16x32_f16(ahh.v, bf, acc2[mf], 0, 0, 0);
            acc2[mf] = __builtin_amdgcn_mfma_f32_16x16x32_f16(all_.v, bf, acc2[mf], 0, 0, 0);
        }
    }
    const float bo = bfc[ocol];
    #pragma unroll
    for (int mf = 0; mf < 2; ++mf)
        #pragma unroll
        for (int i = 0; i < 4; ++i)
            outp[((size_t)z * Lc + row0 + mf * 16 + g * 4 + i) * Dc + ocol] = acc2[mf][i] + bo;
}

// 32x32 transpose + single-f16 convert helper
__device__ __forceinline__ void tr32(const float* src, unsigned short* dh,
                                     int R, int C, int r0, int c0,
                                     float (*tile)[33], int t)
{
    const int tc = t & 31, tr = t >> 5;
    #pragma unroll
    for (int rr = 0; rr < 32; rr += 8)
        tile[tr + rr][tc] = src[(size_t)(r0 + tr + rr) * C + c0 + tc];
    __syncthreads();
    #pragma unroll
    for (int rr = 0; rr < 32; rr += 8) {
        const size_t o = (size_t)(c0 + tr + rr) * R + r0 + tc;
        dh[o] = cv1(tile[tc][tr + rr]);
    }
}

// all weight transposes (single f16) + bias concat in one launch
__global__ __launch_bounds__(256) void prep_k(
    const float* __restrict__ W, const float* __restrict__ Wq,
    const float* __restrict__ Wk, const float* __restrict__ Wv,
    const float* __restrict__ Wfc, const float* __restrict__ bq,
    const float* __restrict__ bk, const float* __restrict__ bv,
    unsigned short* __restrict__ WTf, unsigned short* __restrict__ Wcf,
    unsigned short* __restrict__ WfcTf, float* __restrict__ bcat)
{
    __shared__ float tile[32][33];
    const int bx = blockIdx.x, by = blockIdx.y, t = threadIdx.x;
    if (by == 0) {
        if (bx >= 32) return;
        const int h = bx >> 3, tl = bx & 7;
        tr32(W + (size_t)h * Fc * Dc, WTf + (size_t)h * Dc * Fc,
             Fc, Dc, (tl >> 1) * 32, (tl & 1) * 32, tile, t);
    } else if (by <= 3) {
        const float* s = (by == 1) ? Wq : (by == 2) ? Wk : Wv;
        const size_t off = (size_t)(by - 1) * HDc * HDc;
        tr32(s, Wcf + off, HDc, HDc, (bx >> 3) * 32, (bx & 7) * 32, tile, t);
    } else {
        if (bx < 16) {
            tr32(Wfc, WfcTf, HDc, Dc, (bx >> 1) * 32, (bx & 1) * 32, tile, t);
        } else if (bx == 16) {
            bcat[t] = bq[t]; bcat[256 + t] = bk[t]; bcat[512 + t] = bv[t];
        }
    }
}

extern "C" void kernel_launch(void* const* d_in, const int* in_sizes, int n_in,
                              void* d_out, int out_size, void* d_ws, size_t ws_size,
                              hipStream_t stream)
{
    const float* x   = (const float*)d_in[0];
    const float* W   = (const float*)d_in[1];
    const float* a1  = (const float*)d_in[2];
    const float* a2  = (const float*)d_in[3];
    const float* Wq  = (const float*)d_in[4];
    const float* bq  = (const float*)d_in[5];
    const float* Wk  = (const float*)d_in[6];
    const float* bk  = (const float*)d_in[7];
    const float* Wv  = (const float*)d_in[8];
    const float* bv  = (const float*)d_in[9];
    const float* Wfc = (const float*)d_in[10];
    const float* bfc = (const float*)d_in[11];

    float* outp    = (float*)d_out;
    float* gat_att = outp + (size_t)Bc * Lc * Dc;
    float* t_att   = gat_att + (size_t)Hc * Bc * Lc * Lc;
    float* t_out   = t_att + (size_t)Bc * Lc * Lc;

    constexpr size_t MB = 1024 * 1024;
    char* wsb = (char*)d_ws;
    unsigned short* WhTf = (unsigned short*)wsb;          // 0-8MB, -> VT f16
    unsigned short* VTf  = WhTf;
    unsigned short* gouth = (unsigned short*)(wsb + 8 * MB);   // 8-24MB
    unsigned short* goutl = gouth + (size_t)Nrows * HDc;
    unsigned short* Qh = (unsigned short*)(wsb + 24 * MB);     // 24-40MB
    unsigned short* Ql = Qh + (size_t)Nrows * HDc;
    unsigned short* Kf = (unsigned short*)(wsb + 40 * MB);     // 40-48MB
    float* si  = (float*)(wsb + 48 * MB);
    float* sj  = si + Hc * Nrows;
    float* pstats = sj + Hc * Nrows;                           // [16][16][1024][2]
    unsigned short* WTf = (unsigned short*)(pstats + (size_t)Bc * 16 * Lc * 2);
    unsigned short* Wcf = WTf + Hc * Dc * Fc;                  // [768][256]
    unsigned short* WfcTf = Wcf + 768 * HDc;                   // [64][256]
    float* bcat = (float*)(WfcTf + Dc * HDc);                  // [768]

    const dim3 blk(256);

    // 0. weight prep
    prep_k<<<dim3(64, 5), blk, 0, stream>>>(W, Wq, Wk, Wv, Wfc, bq, bk, bv,
        WTf, Wcf, WfcTf, bcat);

    // 1. WhT f16 = (x @ W[h]^T)^T + fused si/sj
    mm_k<128, 64, A_F32, E_WHT><<<dim3(Nrows / 128, 1, Hc), blk, 0, stream>>>(
        x, nullptr, nullptr, WTf, nullptr, nullptr,
        WhTf, nullptr, nullptr, nullptr,
        Fc, Fc, Fc, 0, 0LL, (long long)Dc * Fc, 0LL, 1.f, a1, a2, si, sj, nullptr);

    // 2. fused GAT: gat_att + gout f16 pair
    gat_k<<<dim3(Lc / 128, 1, 64), blk, 0, stream>>>(si, sj,
        WhTf, gat_att, gouth, goutl);

    // 3. fused QKV projection
    mm_k<128, 128, A_HL, E_QKV><<<dim3(6, Nrows / 128, 1), blk, 0, stream>>>(
        nullptr, gouth, goutl, Wcf, bcat, nullptr,
        Qh, Ql, Kf, VTf,
        HDc, HDc, HDc, HDc, 0LL, 0LL, 0LL, 1.f, nullptr, nullptr, nullptr, nullptr, nullptr);

    // 4. raw scaled scores + partial row stats
    mm_k<128, 128, A_HL, E_STATS><<<dim3(8, 8, Bc), blk, 0, stream>>>(
        nullptr, Qh, Ql, Kf, nullptr, t_att,
        nullptr, nullptr, nullptr, nullptr,
        HDc, HDc, HDc, Lc, (long long)Lc * HDc, (long long)Lc * HDc,
        (long long)Lc * Lc, 0.0625f, nullptr, nullptr, nullptr, nullptr, pstats);

    // 5. PV: folded rstat + fused softmax + t_out + fused out-projection
    pv_k<<<dim3(32, 1, Bc), blk, 0, stream>>>(t_att, pstats, VTf,
        WfcTf, bfc, t_out, outp);
}

// Round 12
// 193.966 us; speedup vs baseline: 1.6129x; 1.0393x over previous
//
#include <hip/hip_runtime.h>

// TemporalGAT on MI355X — round 12: exact restore of round-9 (proven 195 µs).
// f16 2-term split MFMA (A = ah+al f16 pair ~22-bit mantissa; B = single f16).
// 6 launches, XCD swizzle, fused epilogues, 2-phase pipelines.
// B=16, L=1024, F=128, H=4, D=64, HD=256, N=B*L=16384

constexpr int Bc = 16, Lc = 1024, Fc = 128, Hc = 4, Dc = 64, HDc = 256;
constexpr int Nrows = Bc * Lc;  // 16384
#define ALPHA_SLOPE 0.2f

typedef __attribute__((ext_vector_type(8))) _Float16 f16x8;
typedef __attribute__((ext_vector_type(4))) float f32x4;

enum { A_F32 = 0, A_HL = 1 };
enum { E_WHT = 2, E_STATS = 3, E_QKV = 4 };

__device__ __forceinline__ float lrelu(float x) { return x > 0.f ? x : ALPHA_SLOPE * x; }

__device__ __forceinline__ void gll16(const void* g, void* l) {
    __builtin_amdgcn_global_load_lds(
        (const __attribute__((address_space(1))) void*)g,
        (__attribute__((address_space(3))) void*)l, 16, 0, 0);
}

// f32 -> f16 conversions. A-operands: 2-term split (h + residual l).
// B-operands: single f16.
__device__ __forceinline__ unsigned short cv1(float v) {
    union { _Float16 f; unsigned short u; } c; c.f = (_Float16)v; return c.u;
}
__device__ __forceinline__ void sp2(float a, float b, unsigned& h, unsigned& l) {
    const _Float16 ha = (_Float16)a, hb = (_Float16)b;
    union { _Float16 f[2]; unsigned u; } H, L;
    H.f[0] = ha; H.f[1] = hb;
    L.f[0] = (_Float16)(a - (float)ha);
    L.f[1] = (_Float16)(b - (float)hb);
    h = H.u; l = L.u;
}
__device__ __forceinline__ void sp1(float v, unsigned short& h, unsigned short& l) {
    const _Float16 hv = (_Float16)v;
    union { _Float16 f; unsigned short u; } H, L;
    H.f = hv; L.f = (_Float16)(v - (float)hv);
    h = H.u; l = L.u;
}

// ---------------------------------------------------------------------------
// MFMA GEMM, 2-phase double-buffered, XCD-swizzled: C = A[M,K] @ Bt[N,K]^T.
// A = f16 pair (or f32 reg-converted); B = single f16.
// ---------------------------------------------------------------------------
template <int BM, int BN, int AMODE, int EPI>
__global__ __launch_bounds__(256, 2) void mm_k(
    const float* __restrict__ Af,
    const unsigned short* __restrict__ Agh, const unsigned short* __restrict__ Agl,
    const unsigned short* __restrict__ Bg,
    const float* __restrict__ bias,
    float* __restrict__ Cf,
    unsigned short* __restrict__ Ch, unsigned short* __restrict__ Cl,
    unsigned short* __restrict__ Ch2, unsigned short* __restrict__ Ch3,
    int K, int lda, int ldb, int ldc,
    long long zA, long long zB, long long zC, float alpha,
    const float* __restrict__ a1, const float* __restrict__ a2,
    float* __restrict__ si, float* __restrict__ sj, float* __restrict__ pstats)
{
    constexpr int ABUF = BM * 32, BBUF = BN * 32;
    __shared__ __align__(16) unsigned short SM[4 * ABUF + 2 * BBUF];
    unsigned short* const Ah_s = SM;
    unsigned short* const Al_s = SM + 2 * ABUF;
    unsigned short* const Bf_s = SM + 4 * ABUF;

    constexpr bool SWAPXY = (EPI == E_QKV);

    const int nbx = gridDim.x, nby = gridDim.y;
    int lin = blockIdx.x + nbx * (blockIdx.y + nby * blockIdx.z);
    const int ntot = nbx * nby * gridDim.z;
    lin = (lin & 7) * (ntot >> 3) + (lin >> 3);
    const int bx = lin % nbx;
    const int rem = lin / nbx;
    const int by = rem % nby;
    const int z  = rem / nby;

    if (AMODE == A_F32) { Af += (size_t)z * zA; }
    else { Agh += (size_t)z * zA; Agl += (size_t)z * zA; }
    Bg += (size_t)z * zB;
    if (Cf) Cf += (size_t)z * zC;

    constexpr int WC = (BN == 64) ? 1 : 2, WR = 4 / WC;
    constexpr int WM = BM / WR, WN = BN / WC, MF = WM / 16, NF = WN / 16;
    const int row0 = (SWAPXY ? by : bx) * BM;
    const int col0 = (SWAPXY ? bx : by) * BN;
    const int t = threadIdx.x, lane = t & 63, wid = t >> 6;
    const int fr = lane & 15, g = lane >> 4, fk = g * 8;
    const int wrow = (wid / WC) * WM, wcol = (wid % WC) * WN;
    const int rsub = lane >> 2, cbyt = (lane & 3) * 16;

    f32x4 acc[MF][NF] = {};

    auto stageB = [&](int k0, int pp) {
        #pragma unroll
        for (int q = 0; q < BN / 64; ++q) {
            const int r = wid * (BN / 4) + q * 16;
            const size_t gb = ((size_t)(col0 + r + rsub) * ldb + k0) * 2 + cbyt;
            gll16((const char*)Bg + gb, (char*)(Bf_s + pp * BBUF) + (size_t)r * 64);
        }
    };
    auto stageA = [&](int k0, int pp) {
        if (AMODE == A_HL) {
            #pragma unroll
            for (int q = 0; q < BM / 64; ++q) {
                const int r = wid * (BM / 4) + q * 16;
                const size_t gb = ((size_t)(row0 + r + rsub) * lda + k0) * 2 + cbyt;
                gll16((const char*)Agh + gb, (char*)(Ah_s + pp * ABUF) + (size_t)r * 64);
                gll16((const char*)Agl + gb, (char*)(Al_s + pp * ABUF) + (size_t)r * 64);
            }
        } else {
            // f32 -> f16 pair reg-convert staging (BM == 128)
            const int r = t >> 1, h2 = t & 1;
            const float* srcA = Af + (size_t)(row0 + r) * lda + k0 + h2 * 16;
            const float4 v0 = ((const float4*)srcA)[0];
            const float4 v1 = ((const float4*)srcA)[1];
            const float4 v2 = ((const float4*)srcA)[2];
            const float4 v3 = ((const float4*)srcA)[3];
            unsigned hu[8], lu[8];
            sp2(v0.x, v0.y, hu[0], lu[0]); sp2(v0.z, v0.w, hu[1], lu[1]);
            sp2(v1.x, v1.y, hu[2], lu[2]); sp2(v1.z, v1.w, hu[3], lu[3]);
            sp2(v2.x, v2.y, hu[4], lu[4]); sp2(v2.z, v2.w, hu[5], lu[5]);
            sp2(v3.x, v3.y, hu[6], lu[6]); sp2(v3.z, v3.w, hu[7], lu[7]);
            uint4* dh = (uint4*)(Ah_s + pp * ABUF + r * 32 + h2 * 16);
            dh[0] = make_uint4(hu[0], hu[1], hu[2], hu[3]);
            dh[1] = make_uint4(hu[4], hu[5], hu[6], hu[7]);
            uint4* dl = (uint4*)(Al_s + pp * ABUF + r * 32 + h2 * 16);
            dl[0] = make_uint4(lu[0], lu[1], lu[2], lu[3]);
            dl[1] = make_uint4(lu[4], lu[5], lu[6], lu[7]);
        }
    };

    stageB(0, 0);
    stageA(0, 0);
    __syncthreads();

    const int NT = K / 32;
    int p = 0;
    for (int kt = 0; kt < NT; ++kt) {
        if (kt + 1 < NT) { stageB((kt + 1) * 32, p ^ 1); stageA((kt + 1) * 32, p ^ 1); }
        f16x8 ah[MF], al[MF];
        #pragma unroll
        for (int mf = 0; mf < MF; ++mf) {
            const int off = p * ABUF + (wrow + mf * 16 + fr) * 32 + fk;
            ah[mf] = *(const f16x8*)(Ah_s + off);
            al[mf] = *(const f16x8*)(Al_s + off);
        }
        #pragma unroll
        for (int nf = 0; nf < NF; ++nf) {
            const int off = p * BBUF + (wcol + nf * 16 + fr) * 32 + fk;
            const f16x8 bf = *(const f16x8*)(Bf_s + off);
            #pragma unroll
            for (int mf = 0; mf < MF; ++mf) {
                acc[mf][nf] = __builtin_amdgcn_mfma_f32_16x16x32_f16(ah[mf], bf, acc[mf][nf], 0, 0, 0);
                acc[mf][nf] = __builtin_amdgcn_mfma_f32_16x16x32_f16(al[mf], bf, acc[mf][nf], 0, 0, 0);
            }
        }
        __syncthreads();
        p ^= 1;
    }

    // ---- epilogues (C/D layout: col = lane&15, row = (lane>>4)*4 + i [m89])
    float* ts = (float*)SM;  // transpose scratch overlays staging (post-barrier)

    if (EPI == E_STATS) {
        #pragma unroll
        for (int mf = 0; mf < MF; ++mf) {
            #pragma unroll
            for (int i = 0; i < 4; ++i) {
                const size_t row = (size_t)row0 + wrow + mf * 16 + g * 4 + i;
                const size_t co = row * ldc + col0 + wcol + fr;
                #pragma unroll
                for (int nf = 0; nf < NF; ++nf) {
                    float v = acc[mf][nf][i] * alpha;
                    acc[mf][nf][i] = v;
                    Cf[co + nf * 16] = v;
                }
            }
        }
        const int ty = by * WC + (wid % WC);
        #pragma unroll
        for (int mf = 0; mf < MF; ++mf) {
            #pragma unroll
            for (int i = 0; i < 4; ++i) {
                float m = acc[mf][0][i], s;
                #pragma unroll
                for (int nf = 1; nf < NF; ++nf) m = fmaxf(m, acc[mf][nf][i]);
                s = 0.f;
                #pragma unroll
                for (int nf = 0; nf < NF; ++nf) s += __expf(acc[mf][nf][i] - m);
                #pragma unroll
                for (int ofs = 1; ofs < 16; ofs <<= 1) {
                    const float om = __shfl_xor(m, ofs, 64);
                    const float os = __shfl_xor(s, ofs, 64);
                    const float nm = fmaxf(m, om);
                    s = s * __expf(m - nm) + os * __expf(om - nm);
                    m = nm;
                }
                if (fr == 0) {
                    const size_t row = (size_t)row0 + wrow + mf * 16 + g * 4 + i;
                    float* pp = pstats + (((size_t)z * 16 + ty) * Lc + row) * 2;
                    pp[0] = m; pp[1] = s;
                }
            }
        }
    }

    if (EPI == E_QKV) {
        float bv_[NF];
        #pragma unroll
        for (int nf = 0; nf < NF; ++nf) bv_[nf] = bias[col0 + wcol + nf * 16 + fr];
        #pragma unroll
        for (int mf = 0; mf < MF; ++mf)
            #pragma unroll
            for (int i = 0; i < 4; ++i)
                #pragma unroll
                for (int nf = 0; nf < NF; ++nf) acc[mf][nf][i] += bv_[nf];

        if (col0 < 256) {
            // Q (cols 0-255): f16 pair write (A-operand of QK)
            #pragma unroll
            for (int mf = 0; mf < MF; ++mf) {
                #pragma unroll
                for (int i = 0; i < 4; ++i) {
                    const size_t row = (size_t)row0 + wrow + mf * 16 + g * 4 + i;
                    const size_t co = row * ldc + col0 + wcol + fr;
                    #pragma unroll
                    for (int nf = 0; nf < NF; ++nf) {
                        unsigned short hh16, ll16; sp1(acc[mf][nf][i], hh16, ll16);
                        Ch[co + nf * 16] = hh16; Cl[co + nf * 16] = ll16;
                    }
                }
            }
        } else if (col0 < 512) {
            // K (cols 256-511): single f16 write (B-operand of QK)
            const int cl0 = col0 & 255;
            #pragma unroll
            for (int mf = 0; mf < MF; ++mf) {
                #pragma unroll
                for (int i = 0; i < 4; ++i) {
                    const size_t row = (size_t)row0 + wrow + mf * 16 + g * 4 + i;
                    const size_t co = row * ldc + cl0 + wcol + fr;
                    #pragma unroll
                    for (int nf = 0; nf < NF; ++nf)
                        Ch2[co + nf * 16] = cv1(acc[mf][nf][i]);
                }
            }
        } else {
            // V (cols 512-767): transposed single-f16 write -> VT[b][d][l]
            const int bq_ = row0 >> 10, lg0 = row0 & 1023;
            #pragma unroll
            for (int hf = 0; hf < 2; ++hf) {
                if ((wid & 1) == hf) {
                    #pragma unroll
                    for (int mf = 0; mf < MF; ++mf)
                        #pragma unroll
                        for (int i = 0; i < 4; ++i) {
                            const int rr = wrow + mf * 16 + g * 4 + i;
                            #pragma unroll
                            for (int nf = 0; nf < NF; ++nf)
                                ts[rr * 65 + nf * 16 + fr] = acc[mf][nf][i];
                        }
                }
                __syncthreads();
                const int l = t & 127, db = (t >> 7) * 32;
                #pragma unroll
                for (int dd = 0; dd < 32; ++dd) {
                    const int dl = db + dd;
                    const size_t o = ((size_t)bq_ * 256 + (col0 - 512) + hf * 64 + dl) * 1024 + lg0 + l;
                    Ch3[o] = cv1(ts[l * 65 + dl]);
                }
                __syncthreads();
            }
        }
    }

    if (EPI == E_WHT) {
        // si/sj fused reductions (BN==64: each wave spans all 64 cols)
        float a1v[NF], a2v[NF];
        #pragma unroll
        for (int nf = 0; nf < NF; ++nf) {
            a1v[nf] = a1[(size_t)z * Dc + nf * 16 + fr];
            a2v[nf] = a2[(size_t)z * Dc + nf * 16 + fr];
        }
        #pragma unroll
        for (int mf = 0; mf < MF; ++mf) {
            #pragma unroll
            for (int i = 0; i < 4; ++i) {
                float p1 = 0.f, p2 = 0.f;
                #pragma unroll
                for (int nf = 0; nf < NF; ++nf) {
                    p1 = fmaf(acc[mf][nf][i], a1v[nf], p1);
                    p2 = fmaf(acc[mf][nf][i], a2v[nf], p2);
                }
                #pragma unroll
                for (int ofs = 1; ofs < 16; ofs <<= 1) {
                    p1 += __shfl_xor(p1, ofs, 64);
                    p2 += __shfl_xor(p2, ofs, 64);
                }
                if (fr == 0) {
                    const int row = row0 + wrow + mf * 16 + g * 4 + i;
                    si[(size_t)z * Nrows + row] = p1;
                    sj[(size_t)z * Nrows + row] = p2;
                }
            }
        }
        // transposed single-f16 write -> WhT[h*16+b][d][l] (B-operand of gat)
        #pragma unroll
        for (int mf = 0; mf < MF; ++mf)
            #pragma unroll
            for (int i = 0; i < 4; ++i) {
                const int rr = wrow + mf * 16 + g * 4 + i;
                #pragma unroll
                for (int nf = 0; nf < NF; ++nf)
                    ts[rr * 65 + nf * 16 + fr] = acc[mf][nf][i];
            }
        __syncthreads();
        const int bq_ = row0 >> 10, lg0 = row0 & 1023;
        const int l = t & 127, db = (t >> 7) * 32;
        #pragma unroll
        for (int dd = 0; dd < 32; ++dd) {
            const int d = db + dd;
            const size_t o = (((size_t)(z * 16 + bq_)) * 64 + d) * 1024 + lg0 + l;
            Ch[o] = cv1(ts[l * 65 + d]);
        }
    }
}

// ---------------------------------------------------------------------------
// Fused GAT, 2-phase, swizzled, in-block softmax stats. B = single f16.
// ---------------------------------------------------------------------------
__global__ __launch_bounds__(256, 3) void gat_k(
    const float* __restrict__ si, const float* __restrict__ sj,
    const unsigned short* __restrict__ WhTf,
    float* __restrict__ att, unsigned short* __restrict__ gouth,
    unsigned short* __restrict__ goutl)
{
    constexpr int BBUF = 64 * 32;
    __shared__ __align__(16) unsigned short SMg[2 * BBUF];
    __shared__ __align__(16) float sjs[Lc];
    __shared__ float redm[4];
    unsigned short* const Bf_s = SMg;

    // XCD-chunked remap over grid (8,1,64) = 512 blocks
    int lin = blockIdx.x + 8 * blockIdx.z;
    lin = (lin & 7) * 64 + (lin >> 3);
    const int bx = lin & 7, z = lin >> 3;

    const int row0 = bx * 128;
    const int t = threadIdx.x, lane = t & 63, wid = t >> 6;
    const int fr = lane & 15, g = lane >> 4, fk = g * 8;
    const int wrow = wid * 32;
    const int hh = z >> 4, bb = z & 15;
    const int rsub = lane >> 2, cbyt = (lane & 3) * 16;

    const unsigned short* WhTf_z = WhTf + (size_t)z * 64 * 1024;
    const float* sjz = sj + (size_t)z * 1024;
    float* attz = att + ((size_t)z * 1024 + row0) * 1024;

    auto stageB = [&](int j0, int pp) {
        const int r = wid * 16;
        const size_t gb = ((size_t)(r + rsub) * 1024 + j0) * 2 + cbyt;
        gll16((const char*)WhTf_z + gb, (char*)(Bf_s + pp * BBUF) + (size_t)r * 64);
    };

    stageB(0, 0);
    ((float4*)sjs)[t] = ((const float4*)sjz)[t];
    __syncthreads();

    // block-wide max of sj row
    {
        const float4 v = ((const float4*)sjs)[t];
        float m4 = fmaxf(fmaxf(v.x, v.y), fmaxf(v.z, v.w));
        #pragma unroll
        for (int ofs = 32; ofs >= 1; ofs >>= 1) m4 = fmaxf(m4, __shfl_xor(m4, ofs, 64));
        if (lane == 0) redm[wid] = m4;
    }
    __syncthreads();
    const float smax = fmaxf(fmaxf(redm[0], redm[1]), fmaxf(redm[2], redm[3]));

    float siv[2], mr[2], inv[2];
    #pragma unroll
    for (int mf = 0; mf < 2; ++mf) {
        const int r = row0 + wrow + mf * 16 + fr;
        const float sv = si[(size_t)hh * Nrows + bb * 1024 + r];
        siv[mf] = sv;
        mr[mf] = lrelu(sv + smax);
        float s = 0.f;
        const float4* sp = (const float4*)sjs + g * 64;
        #pragma unroll 4
        for (int c = 0; c < 64; ++c) {
            const float4 w = sp[c];
            s += __expf(lrelu(sv + w.x) - mr[mf]) + __expf(lrelu(sv + w.y) - mr[mf])
               + __expf(lrelu(sv + w.z) - mr[mf]) + __expf(lrelu(sv + w.w) - mr[mf]);
        }
        s += __shfl_xor(s, 16, 64);
        s += __shfl_xor(s, 32, 64);
        inv[mf] = 1.0f / s;
    }

    f32x4 acc[2][4] = {};
    int p = 0;
    for (int kt = 0; kt < 32; ++kt) {
        const int j0 = kt * 32;
        if (kt < 31) stageB(j0 + 32, p ^ 1);
        f16x8 ph[2], pl[2];
        #pragma unroll
        for (int mf = 0; mf < 2; ++mf) {
            const float4 s0 = ((const float4*)sjs)[(j0 >> 2) + g * 2];
            const float4 s1 = ((const float4*)sjs)[(j0 >> 2) + g * 2 + 1];
            float pr[8];
            pr[0] = __expf(lrelu(siv[mf] + s0.x) - mr[mf]) * inv[mf];
            pr[1] = __expf(lrelu(siv[mf] + s0.y) - mr[mf]) * inv[mf];
            pr[2] = __expf(lrelu(siv[mf] + s0.z) - mr[mf]) * inv[mf];
            pr[3] = __expf(lrelu(siv[mf] + s0.w) - mr[mf]) * inv[mf];
            pr[4] = __expf(lrelu(siv[mf] + s1.x) - mr[mf]) * inv[mf];
            pr[5] = __expf(lrelu(siv[mf] + s1.y) - mr[mf]) * inv[mf];
            pr[6] = __expf(lrelu(siv[mf] + s1.z) - mr[mf]) * inv[mf];
            pr[7] = __expf(lrelu(siv[mf] + s1.w) - mr[mf]) * inv[mf];
            float* ap = attz + (size_t)(wrow + mf * 16 + fr) * 1024 + j0 + fk;
            *(float4*)ap       = make_float4(pr[0], pr[1], pr[2], pr[3]);
            *(float4*)(ap + 4) = make_float4(pr[4], pr[5], pr[6], pr[7]);
            union { unsigned u[4]; f16x8 v; } uh, ul;
            sp2(pr[0], pr[1], uh.u[0], ul.u[0]);
            sp2(pr[2], pr[3], uh.u[1], ul.u[1]);
            sp2(pr[4], pr[5], uh.u[2], ul.u[2]);
            sp2(pr[6], pr[7], uh.u[3], ul.u[3]);
            ph[mf] = uh.v; pl[mf] = ul.v;
        }
        #pragma unroll
        for (int nf = 0; nf < 4; ++nf) {
            const int off = p * BBUF + (nf * 16 + fr) * 32 + fk;
            const f16x8 bf = *(const f16x8*)(Bf_s + off);
            #pragma unroll
            for (int mf = 0; mf < 2; ++mf) {
                acc[mf][nf] = __builtin_amdgcn_mfma_f32_16x16x32_f16(ph[mf], bf, acc[mf][nf], 0, 0, 0);
                acc[mf][nf] = __builtin_amdgcn_mfma_f32_16x16x32_f16(pl[mf], bf, acc[mf][nf], 0, 0, 0);
            }
        }
        __syncthreads();
        p ^= 1;
    }
    #pragma unroll
    for (int mf = 0; mf < 2; ++mf) {
        #pragma unroll
        for (int i = 0; i < 4; ++i) {
            const int row_l = wrow + mf * 16 + g * 4 + i;
            const size_t base = ((size_t)bb * 1024 + row0 + row_l) * 256 + hh * 64 + fr;
            #pragma unroll
            for (int nf = 0; nf < 4; ++nf) {
                unsigned short hh16, ll16; sp1(acc[mf][nf][i], hh16, ll16);
                gouth[base + nf * 16] = hh16;
                goutl[base + nf * 16] = ll16;
            }
        }
    }
}

// ---------------------------------------------------------------------------
// PV with fused softmax + folded rstat + fused output projection.
// BM=32, BN=256, grid (32,1,16); A = P f16 pair, B = VT single f16.
// t_out written strided from acc concurrently with the LDS stash (round-9).
// ---------------------------------------------------------------------------
__global__ __launch_bounds__(256, 2) void pv_k(
    float* __restrict__ scores, const float* __restrict__ pstats,
    const unsigned short* __restrict__ VTf,
    const unsigned short* __restrict__ WfcTf, const float* __restrict__ bfc,
    float* __restrict__ tout, float* __restrict__ outp)
{
    constexpr int ABUF = 32 * 32, BBUF = 256 * 32;
    __shared__ __align__(16) unsigned short SMp[4 * ABUF + 2 * BBUF];  // 40 KB
    unsigned short* const Ah_s = SMp;
    unsigned short* const Al_s = SMp + 2 * ABUF;
    unsigned short* const Bf_s = SMp + 4 * ABUF;

    // XCD-chunked remap over grid (32,1,16) = 512 blocks
    int lin = blockIdx.x + 32 * blockIdx.z;
    lin = (lin & 7) * 64 + (lin >> 3);
    const int bx = lin & 31, z = lin >> 5;

    const int row0 = bx * 32;
    const int t = threadIdx.x, lane = t & 63, wid = t >> 6;
    const int fr = lane & 15, g = lane >> 4, fk = g * 8;
    const int rsub = lane >> 2, cbyt = (lane & 3) * 16;

    float* sc = scores + ((size_t)z * Lc + row0) * Lc;
    const unsigned short* VTf_z = VTf + (size_t)z * HDc * Lc;

    auto stageB = [&](int k0, int pp) {
        #pragma unroll
        for (int q = 0; q < 4; ++q) {
            const int r = q * 64 + wid * 16;
            const size_t gb = ((size_t)(r + rsub) * Lc + k0) * 2 + cbyt;
            gll16((const char*)VTf_z + gb, (char*)(Bf_s + pp * BBUF) + (size_t)r * 64);
        }
    };

    stageB(0, 0);  // get loads in flight before stats math

    // folded rstat: 8 lanes/row, 2 partials each + 3-step butterfly
    const int ar = t >> 3, cq = (t & 7) * 4;
    float m_ = -1e30f, s_ = 0.f;
    {
        const int q = t & 7;
        const float* pb = pstats + (((size_t)z * 16 + q * 2) * Lc + row0 + ar) * 2;
        #pragma unroll
        for (int j = 0; j < 2; ++j) {
            const float2 pp = *(const float2*)(pb + (size_t)j * Lc * 2);
            const float nm = fmaxf(m_, pp.x);
            s_ = s_ * __expf(m_ - nm) + pp.y * __expf(pp.x - nm);
            m_ = nm;
        }
        #pragma unroll
        for (int ofs = 1; ofs < 8; ofs <<= 1) {
            const float om = __shfl_xor(m_, ofs, 64);
            const float os = __shfl_xor(s_, ofs, 64);
            const float nm = fmaxf(m_, om);
            s_ = s_ * __expf(m_ - nm) + os * __expf(om - nm);
            m_ = nm;
        }
    }
    const float iv_ = 1.0f / s_;

    auto stageA = [&](int k0, int pp) {
        float* srcS = sc + (size_t)ar * Lc + k0 + cq;
        const float4 v0 = *(const float4*)srcS;
        float pr[4];
        pr[0] = __expf(v0.x - m_) * iv_; pr[1] = __expf(v0.y - m_) * iv_;
        pr[2] = __expf(v0.z - m_) * iv_; pr[3] = __expf(v0.w - m_) * iv_;
        *(float4*)srcS = make_float4(pr[0], pr[1], pr[2], pr[3]);
        unsigned hu[2], lu[2];
        sp2(pr[0], pr[1], hu[0], lu[0]); sp2(pr[2], pr[3], hu[1], lu[1]);
        *(uint2*)(Ah_s + pp * ABUF + ar * 32 + cq) = make_uint2(hu[0], hu[1]);
        *(uint2*)(Al_s + pp * ABUF + ar * 32 + cq) = make_uint2(lu[0], lu[1]);
    };

    f32x4 acc[2][4] = {};
    stageA(0, 0);
    __syncthreads();
    int p = 0;
    for (int kt = 0; kt < 32; ++kt) {
        if (kt < 31) { stageB((kt + 1) * 32, p ^ 1); stageA((kt + 1) * 32, p ^ 1); }
        f16x8 ah[2], al[2];
        #pragma unroll
        for (int mf = 0; mf < 2; ++mf) {
            const int off = p * ABUF + (mf * 16 + fr) * 32 + fk;
            ah[mf] = *(const f16x8*)(Ah_s + off);
            al[mf] = *(const f16x8*)(Al_s + off);
        }
        #pragma unroll
        for (int nf = 0; nf < 4; ++nf) {
            const int off = p * BBUF + (wid * 64 + nf * 16 + fr) * 32 + fk;
            const f16x8 bf = *(const f16x8*)(Bf_s + off);
            #pragma unroll
            for (int mf = 0; mf < 2; ++mf) {
                acc[mf][nf] = __builtin_amdgcn_mfma_f32_16x16x32_f16(ah[mf], bf, acc[mf][nf], 0, 0, 0);
                acc[mf][nf] = __builtin_amdgcn_mfma_f32_16x16x32_f16(al[mf], bf, acc[mf][nf], 0, 0, 0);
            }
        }
        __syncthreads();
        p ^= 1;
    }

    // t_out write + stash tile to LDS for the fused output projection
    constexpr int TS = 258;  // f32 row stride (bank-spread)
    float* ts = (float*)SMp;
    #pragma unroll
    for (int mf = 0; mf < 2; ++mf) {
        #pragma unroll
        for (int i = 0; i < 4; ++i) {
            const size_t row = (size_t)row0 + mf * 16 + g * 4 + i;
            float* cp = tout + ((size_t)z * Lc + row) * HDc + wid * 64 + fr;
            #pragma unroll
            for (int nf = 0; nf < 4; ++nf) {
                cp[nf * 16] = acc[mf][nf][i];
                ts[(mf * 16 + g * 4 + i) * TS + wid * 64 + nf * 16 + fr] = acc[mf][nf][i];
            }
        }
    }
    __syncthreads();

    // out = t_out_tile @ WfcT^T + bfc  (K=256; each wave -> 16 out cols)
    const int ocol = wid * 16 + fr;
    f32x4 acc2[2] = {};
    #pragma unroll
    for (int kt2 = 0; kt2 < 8; ++kt2) {
        const int kk = kt2 * 32 + fk;
        const f16x8 bf = *(const f16x8*)(WfcTf + ocol * 256 + kk);
        #pragma unroll
        for (int mf = 0; mf < 2; ++mf) {
            const float* ap = ts + (mf * 16 + fr) * TS + kk;
            union { unsigned u[4]; f16x8 v; } ahh, all_;
            sp2(ap[0], ap[1], ahh.u[0], all_.u[0]);
            sp2(ap[2], ap[3], ahh.u[1], all_.u[1]);
            sp2(ap[4], ap[5], ahh.u[2], all_.u[2]);
            sp2(ap[6], ap[7], ahh.u[3], all_.u[3]);
            acc2[mf] = __builtin_amdgcn_mfma_f32_16x16x32_f16(ahh.v, bf, acc2[mf], 0, 0, 0);
            acc2[mf] = __builtin_amdgcn_mfma_f32_16x16x32_f16(all_.v, bf, acc2[mf], 0, 0, 0);
        }
    }
    const float bo = bfc[ocol];
    #pragma unroll
    for (int mf = 0; mf < 2; ++mf)
        #pragma unroll
        for (int i = 0; i < 4; ++i)
            outp[((size_t)z * Lc + row0 + mf * 16 + g * 4 + i) * Dc + ocol] = acc2[mf][i] + bo;
}

// 32x32 transpose + single-f16 convert helper
__device__ __forceinline__ void tr32(const float* src, unsigned short* dh,
                                     int R, int C, int r0, int c0,
                                     float (*tile)[33], int t)
{
    const int tc = t & 31, tr = t >> 5;
    #pragma unroll
    for (int rr = 0; rr < 32; rr += 8)
        tile[tr + rr][tc] = src[(size_t)(r0 + tr + rr) * C + c0 + tc];
    __syncthreads();
    #pragma unroll
    for (int rr = 0; rr < 32; rr += 8) {
        const size_t o = (size_t)(c0 + tr + rr) * R + r0 + tc;
        dh[o] = cv1(tile[tc][tr + rr]);
    }
}

// all weight transposes (single f16) + bias concat in one launch
__global__ __launch_bounds__(256) void prep_k(
    const float* __restrict__ W, const float* __restrict__ Wq,
    const float* __restrict__ Wk, const float* __restrict__ Wv,
    const float* __restrict__ Wfc, const float* __restrict__ bq,
    const float* __restrict__ bk, const float* __restrict__ bv,
    unsigned short* __restrict__ WTf, unsigned short* __restrict__ Wcf,
    unsigned short* __restrict__ WfcTf, float* __restrict__ bcat)
{
    __shared__ float tile[32][33];
    const int bx = blockIdx.x, by = blockIdx.y, t = threadIdx.x;
    if (by == 0) {
        if (bx >= 32) return;
        const int h = bx >> 3, tl = bx & 7;
        tr32(W + (size_t)h * Fc * Dc, WTf + (size_t)h * Dc * Fc,
             Fc, Dc, (tl >> 1) * 32, (tl & 1) * 32, tile, t);
    } else if (by <= 3) {
        const float* s = (by == 1) ? Wq : (by == 2) ? Wk : Wv;
        const size_t off = (size_t)(by - 1) * HDc * HDc;
        tr32(s, Wcf + off, HDc, HDc, (bx >> 3) * 32, (bx & 7) * 32, tile, t);
    } else {
        if (bx < 16) {
            tr32(Wfc, WfcTf, HDc, Dc, (bx >> 1) * 32, (bx & 1) * 32, tile, t);
        } else if (bx == 16) {
            bcat[t] = bq[t]; bcat[256 + t] = bk[t]; bcat[512 + t] = bv[t];
        }
    }
}

extern "C" void kernel_launch(void* const* d_in, const int* in_sizes, int n_in,
                              void* d_out, int out_size, void* d_ws, size_t ws_size,
                              hipStream_t stream)
{
    const float* x   = (const float*)d_in[0];
    const float* W   = (const float*)d_in[1];
    const float* a1  = (const float*)d_in[2];
    const float* a2  = (const float*)d_in[3];
    const float* Wq  = (const float*)d_in[4];
    const float* bq  = (const float*)d_in[5];
    const float* Wk  = (const float*)d_in[6];
    const float* bk  = (const float*)d_in[7];
    const float* Wv  = (const float*)d_in[8];
    const float* bv  = (const float*)d_in[9];
    const float* Wfc = (const float*)d_in[10];
    const float* bfc = (const float*)d_in[11];

    float* outp    = (float*)d_out;
    float* gat_att = outp + (size_t)Bc * Lc * Dc;
    float* t_att   = gat_att + (size_t)Hc * Bc * Lc * Lc;
    float* t_out   = t_att + (size_t)Bc * Lc * Lc;

    constexpr size_t MB = 1024 * 1024;
    char* wsb = (char*)d_ws;
    unsigned short* WhTf = (unsigned short*)wsb;          // 0-8MB, -> VT f16
    unsigned short* VTf  = WhTf;
    unsigned short* gouth = (unsigned short*)(wsb + 8 * MB);   // 8-24MB
    unsigned short* goutl = gouth + (size_t)Nrows * HDc;
    unsigned short* Qh = (unsigned short*)(wsb + 24 * MB);     // 24-40MB
    unsigned short* Ql = Qh + (size_t)Nrows * HDc;
    unsigned short* Kf = (unsigned short*)(wsb + 40 * MB);     // 40-48MB
    float* si  = (float*)(wsb + 48 * MB);
    float* sj  = si + Hc * Nrows;
    float* pstats = sj + Hc * Nrows;                           // [16][16][1024][2]
    unsigned short* WTf = (unsigned short*)(pstats + (size_t)Bc * 16 * Lc * 2);
    unsigned short* Wcf = WTf + Hc * Dc * Fc;                  // [768][256]
    unsigned short* WfcTf = Wcf + 768 * HDc;                   // [64][256]
    float* bcat = (float*)(WfcTf + Dc * HDc);                  // [768]

    const dim3 blk(256);

    // 0. weight prep (one launch)
    prep_k<<<dim3(64, 5), blk, 0, stream>>>(W, Wq, Wk, Wv, Wfc, bq, bk, bv,
        WTf, Wcf, WfcTf, bcat);

    // 1. WhT f16 = (x @ W[h]^T)^T + fused si/sj
    mm_k<128, 64, A_F32, E_WHT><<<dim3(Nrows / 128, 1, Hc), blk, 0, stream>>>(
        x, nullptr, nullptr, WTf, nullptr, nullptr,
        WhTf, nullptr, nullptr, nullptr,
        Fc, Fc, Fc, 0, 0LL, (long long)Dc * Fc, 0LL, 1.f, a1, a2, si, sj, nullptr);

    // 2. fused GAT (stats in-block): gat_att + gout f16 pair
    gat_k<<<dim3(Lc / 128, 1, 64), blk, 0, stream>>>(si, sj,
        WhTf, gat_att, gouth, goutl);

    // 3. fused QKV projection (col-block on x for XCD A-panel sharing)
    mm_k<128, 128, A_HL, E_QKV><<<dim3(6, Nrows / 128, 1), blk, 0, stream>>>(
        nullptr, gouth, goutl, Wcf, bcat, nullptr,
        Qh, Ql, Kf, VTf,
        HDc, HDc, HDc, HDc, 0LL, 0LL, 0LL, 1.f, nullptr, nullptr, nullptr, nullptr, nullptr);

    // 4. raw scaled scores -> t_att region + partial row stats
    mm_k<128, 128, A_HL, E_STATS><<<dim3(8, 8, Bc), blk, 0, stream>>>(
        nullptr, Qh, Ql, Kf, nullptr, t_att,
        nullptr, nullptr, nullptr, nullptr,
        HDc, HDc, HDc, Lc, (long long)Lc * HDc, (long long)Lc * HDc,
        (long long)Lc * Lc, 0.0625f, nullptr, nullptr, nullptr, nullptr, pstats);

    // 5. PV: folded rstat + fused softmax + t_out + fused out-projection
    pv_k<<<dim3(32, 1, Bc), blk, 0, stream>>>(t_att, pstats, VTf,
        WfcTf, bfc, t_out, outp);
}